// Round 1
// baseline (1849.178 us; speedup 1.0000x reference)
//
#include <hip/hip_runtime.h>
#include <hip/hip_bf16.h>

#define NN 50000
#define EE 800000
#define DD 128
#define HH 4
#define DHH 32
#define NEG_SLOPE 0.2f

// ---------------- proj: feat0 = x@W0, feat1 = x@W1, out = x@Wl + bias ----------
__global__ __launch_bounds__(256) void proj_kernel(
    const float* __restrict__ x, const float* __restrict__ W0,
    const float* __restrict__ W1, const float* __restrict__ Wl,
    const float* __restrict__ bias,
    float* __restrict__ feat0, float* __restrict__ feat1, float* __restrict__ out)
{
    __shared__ float xs[64][132];          // +4 pad: conflict-free column reads
    __shared__ float wt[32 * 128];         // one 32-row K-chunk of W

    const int t = threadIdx.x;
    const int row0 = blockIdx.x * 64;

    // load 64 rows of x (8192 floats) as float4, coalesced
    for (int i = 0; i < 8; ++i) {
        int idx = t + i * 256;             // float4 index, 0..2047
        int r = idx >> 5;                  // 32 float4 per row
        int c4 = idx & 31;
        float4 v = make_float4(0.f, 0.f, 0.f, 0.f);
        if (row0 + r < NN) v = ((const float4*)x)[(size_t)(row0 + r) * 32 + c4];
        *(float4*)&xs[r][c4 * 4] = v;      // row stride 132 -> 16B aligned
    }
    __syncthreads();

    const int rA = t >> 3;                 // 0..31 (thread's first row)
    const int c0 = (t & 7) * 16;           // 16 consecutive output cols

    const float* Ws[3] = {W0, W1, Wl};

    for (int m = 0; m < 3; ++m) {
        float acc0[16], acc1[16];
        #pragma unroll
        for (int j = 0; j < 16; ++j) { acc0[j] = 0.f; acc1[j] = 0.f; }

        const float* __restrict__ W = Ws[m];
        for (int kc = 0; kc < 4; ++kc) {
            __syncthreads();               // previous wt consumers done
            for (int i = 0; i < 4; ++i) {  // stage 32x128 chunk of W
                int idx = t + i * 256;     // float4 idx 0..1023
                ((float4*)wt)[idx] = ((const float4*)W)[kc * 1024 + idx];
            }
            __syncthreads();
            #pragma unroll 8
            for (int kk = 0; kk < 32; ++kk) {
                int k = kc * 32 + kk;
                float xa = xs[rA][k];
                float xb = xs[rA + 32][k];
                const float* wrow = &wt[kk * 128 + c0];
                #pragma unroll
                for (int j = 0; j < 16; ++j) {
                    float wv = wrow[j];
                    acc0[j] += xa * wv;
                    acc1[j] += xb * wv;
                }
            }
        }

        // epilogue
        int ra = row0 + rA, rb = row0 + rA + 32;
        if (m < 2) {
            float* dst = (m == 0) ? feat0 : feat1;
            if (ra < NN) {
                #pragma unroll
                for (int q = 0; q < 4; ++q)
                    *(float4*)&dst[(size_t)ra * DD + c0 + q * 4] = *(float4*)&acc0[q * 4];
            }
            if (rb < NN) {
                #pragma unroll
                for (int q = 0; q < 4; ++q)
                    *(float4*)&dst[(size_t)rb * DD + c0 + q * 4] = *(float4*)&acc1[q * 4];
            }
        } else {
            float bv[16];
            #pragma unroll
            for (int q = 0; q < 4; ++q)
                *(float4*)&bv[q * 4] = *(const float4*)&bias[c0 + q * 4];
            if (ra < NN) {
                #pragma unroll
                for (int q = 0; q < 4; ++q) {
                    float4 v;
                    v.x = acc0[q*4+0] + bv[q*4+0]; v.y = acc0[q*4+1] + bv[q*4+1];
                    v.z = acc0[q*4+2] + bv[q*4+2]; v.w = acc0[q*4+3] + bv[q*4+3];
                    *(float4*)&out[(size_t)ra * DD + c0 + q * 4] = v;
                }
            }
            if (rb < NN) {
                #pragma unroll
                for (int q = 0; q < 4; ++q) {
                    float4 v;
                    v.x = acc1[q*4+0] + bv[q*4+0]; v.y = acc1[q*4+1] + bv[q*4+1];
                    v.z = acc1[q*4+2] + bv[q*4+2]; v.w = acc1[q*4+3] + bv[q*4+3];
                    *(float4*)&out[(size_t)rb * DD + c0 + q * 4] = v;
                }
            }
        }
    }
}

// ---------------- attention dot products: el/er for both relations ------------
__global__ __launch_bounds__(256) void attn_dots_kernel(
    const float* __restrict__ feat0, const float* __restrict__ feat1,
    const float* __restrict__ al0, const float* __restrict__ ar0,
    const float* __restrict__ al1, const float* __restrict__ ar1,
    float* __restrict__ el0, float* __restrict__ er0,
    float* __restrict__ el1, float* __restrict__ er1)
{
    int idx = blockIdx.x * 256 + threadIdx.x;   // (n,h)
    if (idx >= NN * HH) return;
    int n = idx >> 2, h = idx & 3;

    const float4* f0 = (const float4*)&feat0[(size_t)n * DD + h * DHH];
    const float4* f1 = (const float4*)&feat1[(size_t)n * DD + h * DHH];
    const float4* a0 = (const float4*)&al0[h * DHH];
    const float4* b0 = (const float4*)&ar0[h * DHH];
    const float4* a1 = (const float4*)&al1[h * DHH];
    const float4* b1 = (const float4*)&ar1[h * DHH];

    float sl0 = 0.f, sr0 = 0.f, sl1 = 0.f, sr1 = 0.f;
    #pragma unroll
    for (int q = 0; q < 8; ++q) {
        float4 v = f0[q], a = a0[q], b = b0[q];
        sl0 += v.x*a.x + v.y*a.y + v.z*a.z + v.w*a.w;
        sr0 += v.x*b.x + v.y*b.y + v.z*b.z + v.w*b.w;
        float4 w = f1[q], c = a1[q], d = b1[q];
        sl1 += w.x*c.x + w.y*c.y + w.z*c.z + w.w*c.w;
        sr1 += w.x*d.x + w.y*d.y + w.z*d.z + w.w*d.w;
    }
    el0[idx] = sl0; er0[idx] = sr0;
    el1[idx] = sl1; er1[idx] = sr1;
}

// ---------------- denom: softmax denominator per (dst,h), no max-sub ----------
__global__ __launch_bounds__(256) void edge_denom_kernel(
    const int* __restrict__ src, const int* __restrict__ dst,
    const float* __restrict__ el, const float* __restrict__ er,
    float* __restrict__ denom)
{
    int e = blockIdx.x * 256 + threadIdx.x;
    if (e >= EE) return;
    int s = src[e], d = dst[e];
    float4 l = *(const float4*)&el[(size_t)s * 4];
    float4 r = *(const float4*)&er[(size_t)d * 4];
    float v[4] = {l.x + r.x, l.y + r.y, l.z + r.z, l.w + r.w};
    #pragma unroll
    for (int h = 0; h < 4; ++h) {
        float e_h = v[h] > 0.f ? v[h] : NEG_SLOPE * v[h];
        unsafeAtomicAdd(&denom[(size_t)d * 4 + h], __expf(e_h));
    }
}

// ---------------- aggregate: out[dst] += alpha * feat[src] -------------------
__global__ __launch_bounds__(256) void edge_agg_kernel(
    const int* __restrict__ src, const int* __restrict__ dst,
    const float* __restrict__ el, const float* __restrict__ er,
    const float* __restrict__ denom, const float* __restrict__ feat,
    float* __restrict__ out)
{
    int wave = (blockIdx.x * 256 + threadIdx.x) >> 6;   // one wave per edge
    int lane = threadIdx.x & 63;
    if (wave >= EE) return;
    int s = src[wave], d = dst[wave];
    int h = lane >> 4;                                   // 16 lanes per head
    float e = el[(size_t)s * 4 + h] + er[(size_t)d * 4 + h];
    e = e > 0.f ? e : NEG_SLOPE * e;
    float alpha = __expf(e) / denom[(size_t)d * 4 + h];
    float2 f = *(const float2*)&feat[(size_t)s * DD + lane * 2];
    unsafeAtomicAdd(&out[(size_t)d * DD + lane * 2 + 0], alpha * f.x);
    unsafeAtomicAdd(&out[(size_t)d * DD + lane * 2 + 1], alpha * f.y);
}

// ---------------- final ReLU in place ----------------------------------------
__global__ __launch_bounds__(256) void relu_kernel(float* __restrict__ out)
{
    int i = blockIdx.x * 256 + threadIdx.x;   // float4 index; N*DD/4 = 1.6M exact
    float4 v = ((float4*)out)[i];
    v.x = fmaxf(v.x, 0.f); v.y = fmaxf(v.y, 0.f);
    v.z = fmaxf(v.z, 0.f); v.w = fmaxf(v.w, 0.f);
    ((float4*)out)[i] = v;
}

extern "C" void kernel_launch(void* const* d_in, const int* in_sizes, int n_in,
                              void* d_out, int out_size, void* d_ws, size_t ws_size,
                              hipStream_t stream)
{
    const float* x    = (const float*)d_in[0];
    const float* W0   = (const float*)d_in[1];
    const float* al0  = (const float*)d_in[2];
    const float* ar0  = (const float*)d_in[3];
    const float* W1   = (const float*)d_in[4];
    const float* al1  = (const float*)d_in[5];
    const float* ar1  = (const float*)d_in[6];
    const float* Wl   = (const float*)d_in[7];
    const float* bias = (const float*)d_in[8];
    const int* src0   = (const int*)d_in[9];
    const int* dst0   = (const int*)d_in[10];
    const int* src1   = (const int*)d_in[11];
    const int* dst1   = (const int*)d_in[12];
    float* out = (float*)d_out;

    // workspace layout (floats)
    float* ws    = (float*)d_ws;
    float* feat0 = ws;                       // N*128
    float* feat1 = feat0 + (size_t)NN * DD;  // N*128
    float* el0   = feat1 + (size_t)NN * DD;  // N*4 each below
    float* er0   = el0 + (size_t)NN * HH;
    float* el1   = er0 + (size_t)NN * HH;
    float* er1   = el1 + (size_t)NN * HH;
    float* den0  = er1 + (size_t)NN * HH;
    float* den1  = den0 + (size_t)NN * HH;

    hipMemsetAsync(den0, 0, (size_t)2 * NN * HH * sizeof(float), stream);

    proj_kernel<<<dim3((NN + 63) / 64), dim3(256), 0, stream>>>(
        x, W0, W1, Wl, bias, feat0, feat1, out);

    attn_dots_kernel<<<dim3((NN * HH + 255) / 256), dim3(256), 0, stream>>>(
        feat0, feat1, al0, ar0, al1, ar1, el0, er0, el1, er1);

    edge_denom_kernel<<<dim3((EE + 255) / 256), dim3(256), 0, stream>>>(
        src0, dst0, el0, er0, den0);
    edge_denom_kernel<<<dim3((EE + 255) / 256), dim3(256), 0, stream>>>(
        src1, dst1, el1, er1, den1);

    edge_agg_kernel<<<dim3(EE / 4), dim3(256), 0, stream>>>(
        src0, dst0, el0, er0, den0, feat0, out);
    edge_agg_kernel<<<dim3(EE / 4), dim3(256), 0, stream>>>(
        src1, dst1, el1, er1, den1, feat1, out);

    relu_kernel<<<dim3(NN * DD / 4 / 256), dim3(256), 0, stream>>>(out);
}

// Round 2
// 625.029 us; speedup vs baseline: 2.9585x; 2.9585x over previous
//
#include <hip/hip_runtime.h>
#include <hip/hip_bf16.h>

#define NN 50000
#define EE 800000
#define DD 128
#define HH 4
#define DHH 32
#define NEG_SLOPE 0.2f

// ---------------- proj: feat0 = x@W0, feat1 = x@W1, out = x@Wl + bias ----------
__global__ __launch_bounds__(256) void proj_kernel(
    const float* __restrict__ x, const float* __restrict__ W0,
    const float* __restrict__ W1, const float* __restrict__ Wl,
    const float* __restrict__ bias,
    float* __restrict__ feat0, float* __restrict__ feat1, float* __restrict__ out)
{
    __shared__ float xs[64][132];          // +4 pad: conflict-free column reads
    __shared__ float wt[32 * 128];         // one 32-row K-chunk of W

    const int t = threadIdx.x;
    const int row0 = blockIdx.x * 64;

    for (int i = 0; i < 8; ++i) {
        int idx = t + i * 256;             // float4 index, 0..2047
        int r = idx >> 5;
        int c4 = idx & 31;
        float4 v = make_float4(0.f, 0.f, 0.f, 0.f);
        if (row0 + r < NN) v = ((const float4*)x)[(size_t)(row0 + r) * 32 + c4];
        *(float4*)&xs[r][c4 * 4] = v;
    }
    __syncthreads();

    const int rA = t >> 3;                 // 0..31
    const int c0 = (t & 7) * 16;           // 16 consecutive output cols

    const float* Ws[3] = {W0, W1, Wl};

    for (int m = 0; m < 3; ++m) {
        float acc0[16], acc1[16];
        #pragma unroll
        for (int j = 0; j < 16; ++j) { acc0[j] = 0.f; acc1[j] = 0.f; }

        const float* __restrict__ W = Ws[m];
        for (int kc = 0; kc < 4; ++kc) {
            __syncthreads();
            for (int i = 0; i < 4; ++i) {
                int idx = t + i * 256;
                ((float4*)wt)[idx] = ((const float4*)W)[kc * 1024 + idx];
            }
            __syncthreads();
            #pragma unroll 8
            for (int kk = 0; kk < 32; ++kk) {
                int k = kc * 32 + kk;
                float xa = xs[rA][k];
                float xb = xs[rA + 32][k];
                const float* wrow = &wt[kk * 128 + c0];
                #pragma unroll
                for (int j = 0; j < 16; ++j) {
                    float wv = wrow[j];
                    acc0[j] += xa * wv;
                    acc1[j] += xb * wv;
                }
            }
        }

        int ra = row0 + rA, rb = row0 + rA + 32;
        if (m < 2) {
            float* dst = (m == 0) ? feat0 : feat1;
            if (ra < NN) {
                #pragma unroll
                for (int q = 0; q < 4; ++q)
                    *(float4*)&dst[(size_t)ra * DD + c0 + q * 4] = *(float4*)&acc0[q * 4];
            }
            if (rb < NN) {
                #pragma unroll
                for (int q = 0; q < 4; ++q)
                    *(float4*)&dst[(size_t)rb * DD + c0 + q * 4] = *(float4*)&acc1[q * 4];
            }
        } else {
            float bv[16];
            #pragma unroll
            for (int q = 0; q < 4; ++q)
                *(float4*)&bv[q * 4] = *(const float4*)&bias[c0 + q * 4];
            if (ra < NN) {
                #pragma unroll
                for (int q = 0; q < 4; ++q) {
                    float4 v;
                    v.x = acc0[q*4+0] + bv[q*4+0]; v.y = acc0[q*4+1] + bv[q*4+1];
                    v.z = acc0[q*4+2] + bv[q*4+2]; v.w = acc0[q*4+3] + bv[q*4+3];
                    *(float4*)&out[(size_t)ra * DD + c0 + q * 4] = v;
                }
            }
            if (rb < NN) {
                #pragma unroll
                for (int q = 0; q < 4; ++q) {
                    float4 v;
                    v.x = acc1[q*4+0] + bv[q*4+0]; v.y = acc1[q*4+1] + bv[q*4+1];
                    v.z = acc1[q*4+2] + bv[q*4+2]; v.w = acc1[q*4+3] + bv[q*4+3];
                    *(float4*)&out[(size_t)rb * DD + c0 + q * 4] = v;
                }
            }
        }
    }
}

// ---------------- attention dot products: el/er for both relations ------------
__global__ __launch_bounds__(256) void attn_dots_kernel(
    const float* __restrict__ feat0, const float* __restrict__ feat1,
    const float* __restrict__ al0, const float* __restrict__ ar0,
    const float* __restrict__ al1, const float* __restrict__ ar1,
    float* __restrict__ el0, float* __restrict__ er0,
    float* __restrict__ el1, float* __restrict__ er1)
{
    int idx = blockIdx.x * 256 + threadIdx.x;   // (n,h)
    if (idx >= NN * HH) return;
    int n = idx >> 2, h = idx & 3;

    const float4* f0 = (const float4*)&feat0[(size_t)n * DD + h * DHH];
    const float4* f1 = (const float4*)&feat1[(size_t)n * DD + h * DHH];
    const float4* a0 = (const float4*)&al0[h * DHH];
    const float4* b0 = (const float4*)&ar0[h * DHH];
    const float4* a1 = (const float4*)&al1[h * DHH];
    const float4* b1 = (const float4*)&ar1[h * DHH];

    float sl0 = 0.f, sr0 = 0.f, sl1 = 0.f, sr1 = 0.f;
    #pragma unroll
    for (int q = 0; q < 8; ++q) {
        float4 v = f0[q], a = a0[q], b = b0[q];
        sl0 += v.x*a.x + v.y*a.y + v.z*a.z + v.w*a.w;
        sr0 += v.x*b.x + v.y*b.y + v.z*b.z + v.w*b.w;
        float4 w = f1[q], c = a1[q], d = b1[q];
        sl1 += w.x*c.x + w.y*c.y + w.z*c.z + w.w*c.w;
        sr1 += w.x*d.x + w.y*d.y + w.z*d.z + w.w*d.w;
    }
    el0[idx] = sl0; er0[idx] = sr0;
    el1[idx] = sl1; er1[idx] = sr1;
}

// ---------------- CSR build: histogram ---------------------------------------
__global__ __launch_bounds__(256) void hist_kernel(
    const int* __restrict__ dst0, const int* __restrict__ dst1,
    int* __restrict__ deg0, int* __restrict__ deg1)
{
    int e = blockIdx.x * 256 + threadIdx.x;
    if (e < EE)               atomicAdd(&deg0[dst0[e]], 1);
    else if (e < 2 * EE)      atomicAdd(&deg1[dst1[e - EE]], 1);
}

// ---------------- CSR build: exclusive scan (one block per relation) ----------
__global__ __launch_bounds__(1024) void scan_kernel(
    const int* __restrict__ deg0, int* __restrict__ row0,
    const int* __restrict__ deg1, int* __restrict__ row1)
{
    const int* __restrict__ deg = blockIdx.x ? deg1 : deg0;
    int* __restrict__ row = blockIdx.x ? row1 : row0;
    __shared__ int wtot[16];
    __shared__ int carry_s;
    const int t = threadIdx.x;
    const int lane = t & 63, wave = t >> 6;
    if (t == 0) carry_s = 0;
    __syncthreads();
    for (int base = 0; base < NN; base += 1024) {
        int idx = base + t;
        int v = (idx < NN) ? deg[idx] : 0;
        int incl = v;
        #pragma unroll
        for (int off = 1; off < 64; off <<= 1) {
            int u = __shfl_up(incl, off);
            if (lane >= off) incl += u;
        }
        if (lane == 63) wtot[wave] = incl;
        __syncthreads();
        int carry = carry_s;
        int woff = 0;
        #pragma unroll
        for (int w = 0; w < 16; ++w) woff += (w < wave) ? wtot[w] : 0;
        if (idx < NN) row[idx] = carry + woff + incl - v;   // exclusive
        __syncthreads();
        if (t == 1023) carry_s = carry + woff + incl;
        __syncthreads();
    }
}

// ---------------- CSR build: scatter (row[d] becomes segment END) -------------
__global__ __launch_bounds__(256) void scatter_kernel(
    const int* __restrict__ src0, const int* __restrict__ dst0,
    int* __restrict__ row0, int* __restrict__ list0,
    const int* __restrict__ src1, const int* __restrict__ dst1,
    int* __restrict__ row1, int* __restrict__ list1)
{
    int e = blockIdx.x * 256 + threadIdx.x;
    if (e < EE) {
        int pos = atomicAdd(&row0[dst0[e]], 1);
        list0[pos] = src0[e];
    } else if (e < 2 * EE) {
        int i = e - EE;
        int pos = atomicAdd(&row1[dst1[i]], 1);
        list1[pos] = src1[i];
    }
}

// ---------------- aggregate: one wave per dst node, both relations ------------
__global__ __launch_bounds__(256) void agg_kernel(
    const int* __restrict__ row0, const int* __restrict__ list0,
    const float* __restrict__ el0, const float* __restrict__ er0,
    const int* __restrict__ row1, const int* __restrict__ list1,
    const float* __restrict__ el1, const float* __restrict__ er1,
    const float* __restrict__ feat0, const float* __restrict__ feat1,
    float* __restrict__ out)
{
    const int d = blockIdx.x * 4 + (threadIdx.x >> 6);
    const int lane = threadIdx.x & 63;
    if (d >= NN) return;

    // post-scatter: row[d] = end of segment d; start = row[d-1] (or 0)
    const int s0 = d ? row0[d - 1] : 0, e0 = row0[d];
    const int s1 = d ? row1[d - 1] : 0, e1 = row1[d];

    const float4 erd0 = *(const float4*)&er0[(size_t)d * 4];
    const float4 erd1 = *(const float4*)&er1[(size_t)d * 4];

    // pass 1: softmax denominators (4 heads x 2 relations), lane-strided
    float d0x = 0.f, d0y = 0.f, d0z = 0.f, d0w = 0.f;
    float d1x = 0.f, d1y = 0.f, d1z = 0.f, d1w = 0.f;
    for (int i = s0 + lane; i < e0; i += 64) {
        int s = list0[i];
        float4 l = *(const float4*)&el0[(size_t)s * 4];
        float v;
        v = l.x + erd0.x; d0x += __expf(v > 0.f ? v : NEG_SLOPE * v);
        v = l.y + erd0.y; d0y += __expf(v > 0.f ? v : NEG_SLOPE * v);
        v = l.z + erd0.z; d0z += __expf(v > 0.f ? v : NEG_SLOPE * v);
        v = l.w + erd0.w; d0w += __expf(v > 0.f ? v : NEG_SLOPE * v);
    }
    for (int i = s1 + lane; i < e1; i += 64) {
        int s = list1[i];
        float4 l = *(const float4*)&el1[(size_t)s * 4];
        float v;
        v = l.x + erd1.x; d1x += __expf(v > 0.f ? v : NEG_SLOPE * v);
        v = l.y + erd1.y; d1y += __expf(v > 0.f ? v : NEG_SLOPE * v);
        v = l.z + erd1.z; d1z += __expf(v > 0.f ? v : NEG_SLOPE * v);
        v = l.w + erd1.w; d1w += __expf(v > 0.f ? v : NEG_SLOPE * v);
    }
    #pragma unroll
    for (int m = 32; m; m >>= 1) {
        d0x += __shfl_xor(d0x, m); d0y += __shfl_xor(d0y, m);
        d0z += __shfl_xor(d0z, m); d0w += __shfl_xor(d0w, m);
        d1x += __shfl_xor(d1x, m); d1y += __shfl_xor(d1y, m);
        d1z += __shfl_xor(d1z, m); d1w += __shfl_xor(d1w, m);
    }

    const int h = lane >> 4;              // 16 lanes per head
    const int c = lane * 2;               // 2 output columns per lane
    const float erh0 = (h == 0) ? erd0.x : (h == 1) ? erd0.y : (h == 2) ? erd0.z : erd0.w;
    const float erh1 = (h == 0) ? erd1.x : (h == 1) ? erd1.y : (h == 2) ? erd1.z : erd1.w;
    const float dh0  = (h == 0) ? d0x : (h == 1) ? d0y : (h == 2) ? d0z : d0w;
    const float dh1  = (h == 0) ? d1x : (h == 1) ? d1y : (h == 2) ? d1z : d1w;
    const float inv0 = (e0 > s0) ? 1.f / dh0 : 0.f;
    const float inv1 = (e1 > s1) ? 1.f / dh1 : 0.f;

    float accx = 0.f, accy = 0.f;
    for (int i = s0; i < e0; ++i) {
        int s = list0[i];                                  // wave-uniform broadcast
        float ev = el0[(size_t)s * 4 + h] + erh0;
        ev = ev > 0.f ? ev : NEG_SLOPE * ev;
        float a = __expf(ev) * inv0;
        float2 f = *(const float2*)&feat0[(size_t)s * DD + c];
        accx += a * f.x; accy += a * f.y;
    }
    for (int i = s1; i < e1; ++i) {
        int s = list1[i];
        float ev = el1[(size_t)s * 4 + h] + erh1;
        ev = ev > 0.f ? ev : NEG_SLOPE * ev;
        float a = __expf(ev) * inv1;
        float2 f = *(const float2*)&feat1[(size_t)s * DD + c];
        accx += a * f.x; accy += a * f.y;
    }

    // out already holds x@Wl + bias; add messages, fuse ReLU
    float2 o = *(float2*)&out[(size_t)d * DD + c];
    o.x = fmaxf(o.x + accx, 0.f);
    o.y = fmaxf(o.y + accy, 0.f);
    *(float2*)&out[(size_t)d * DD + c] = o;
}

extern "C" void kernel_launch(void* const* d_in, const int* in_sizes, int n_in,
                              void* d_out, int out_size, void* d_ws, size_t ws_size,
                              hipStream_t stream)
{
    const float* x    = (const float*)d_in[0];
    const float* W0   = (const float*)d_in[1];
    const float* al0  = (const float*)d_in[2];
    const float* ar0  = (const float*)d_in[3];
    const float* W1   = (const float*)d_in[4];
    const float* al1  = (const float*)d_in[5];
    const float* ar1  = (const float*)d_in[6];
    const float* Wl   = (const float*)d_in[7];
    const float* bias = (const float*)d_in[8];
    const int* src0   = (const int*)d_in[9];
    const int* dst0   = (const int*)d_in[10];
    const int* src1   = (const int*)d_in[11];
    const int* dst1   = (const int*)d_in[12];
    float* out = (float*)d_out;

    // workspace layout (4-byte elements)
    float* ws    = (float*)d_ws;
    float* feat0 = ws;                         // N*128
    float* feat1 = feat0 + (size_t)NN * DD;    // N*128
    float* el0   = feat1 + (size_t)NN * DD;
    float* er0   = el0 + (size_t)NN * HH;
    float* el1   = er0 + (size_t)NN * HH;
    float* er1   = el1 + (size_t)NN * HH;
    int* deg0    = (int*)(er1 + (size_t)NN * HH);
    int* deg1    = deg0 + NN;
    int* row0    = deg1 + NN;
    int* row1    = row0 + NN;
    int* list0   = row1 + NN;                  // E each
    int* list1   = list0 + EE;

    hipMemsetAsync(deg0, 0, (size_t)2 * NN * sizeof(int), stream);

    proj_kernel<<<dim3((NN + 63) / 64), dim3(256), 0, stream>>>(
        x, W0, W1, Wl, bias, feat0, feat1, out);

    attn_dots_kernel<<<dim3((NN * HH + 255) / 256), dim3(256), 0, stream>>>(
        feat0, feat1, al0, ar0, al1, ar1, el0, er0, el1, er1);

    hist_kernel<<<dim3((2 * EE + 255) / 256), dim3(256), 0, stream>>>(
        dst0, dst1, deg0, deg1);

    scan_kernel<<<dim3(2), dim3(1024), 0, stream>>>(deg0, row0, deg1, row1);

    scatter_kernel<<<dim3((2 * EE + 255) / 256), dim3(256), 0, stream>>>(
        src0, dst0, row0, list0, src1, dst1, row1, list1);

    agg_kernel<<<dim3((NN + 3) / 4), dim3(256), 0, stream>>>(
        row0, list0, el0, er0, row1, list1, el1, er1, feat0, feat1, out);
}

// Round 3
// 544.874 us; speedup vs baseline: 3.3938x; 1.1471x over previous
//
#include <hip/hip_runtime.h>
#include <hip/hip_bf16.h>

#define NN 50000
#define EE 800000
#define DD 128
#define HH 4
#define NEG_SLOPE 0.2f

typedef __attribute__((ext_vector_type(8))) short bf16x8;
typedef __attribute__((ext_vector_type(4))) float f32x4;

static __device__ __forceinline__ float bf2f(ushort u) {
    union { unsigned int ui; float f; } v; v.ui = ((unsigned int)u) << 16; return v.f;
}
static __device__ __forceinline__ void split1(float v, ushort& h, ushort& l) {
    __hip_bfloat16 hb = __float2bfloat16(v);
    float hf = __bfloat162float(hb);
    __hip_bfloat16 lb = __float2bfloat16(v - hf);
    h = *(ushort*)&hb; l = *(ushort*)&lb;
}

// ---------------- x -> (x_hi, x_lo) bf16 split --------------------------------
__global__ __launch_bounds__(256) void xcvt_kernel(
    const float* __restrict__ x, ushort* __restrict__ xh, ushort* __restrict__ xl)
{
    int i = blockIdx.x * 256 + threadIdx.x;      // float4 idx; NN*DD/4 = 1.6M exact
    if (i >= NN * DD / 4) return;
    float4 v = ((const float4*)x)[i];
    ushort4 h, l;
    split1(v.x, h.x, l.x); split1(v.y, h.y, l.y);
    split1(v.z, h.z, l.z); split1(v.w, h.w, l.w);
    *(ushort4*)&xh[(size_t)i * 4] = h;
    *(ushort4*)&xl[(size_t)i * 4] = l;
}

// ---------------- W -> W^T (hi,lo) bf16; wt layout [3][2][128n][128k] ---------
__global__ __launch_bounds__(256) void wcvt_kernel(
    const float* __restrict__ W0, const float* __restrict__ W1,
    const float* __restrict__ Wl, ushort* __restrict__ wt)
{
    int m = blockIdx.x >> 6;                     // 64 blocks per matrix
    int b = blockIdx.x & 63;
    const float* W = (m == 0) ? W0 : (m == 1) ? W1 : Wl;
    int idx = b * 256 + threadIdx.x;             // 0..16383
    int k = idx >> 7, n = idx & 127;
    ushort h, l; split1(W[idx], h, l);
    wt[((size_t)m * 2 + 0) * 16384 + (size_t)n * 128 + k] = h;
    wt[((size_t)m * 2 + 1) * 16384 + (size_t)n * 128 + k] = l;
}

// ---------------- proj: MFMA, fused el/er + bias + bf16 feat ------------------
// 256 thr = 4 waves; block does 64 rows; wave owns 16 rows x 128 cols.
__global__ __launch_bounds__(256) void proj_kernel(
    const ushort* __restrict__ xh, const ushort* __restrict__ xl,
    const ushort* __restrict__ wt,
    const float* __restrict__ al0, const float* __restrict__ ar0,
    const float* __restrict__ al1, const float* __restrict__ ar1,
    const float* __restrict__ bias,
    ushort* __restrict__ fb0, ushort* __restrict__ fb1,
    float* __restrict__ el0, float* __restrict__ er0,
    float* __restrict__ el1, float* __restrict__ er1,
    float* __restrict__ out)
{
    const int lane = threadIdx.x & 63;
    const int wave = threadIdx.x >> 6;
    const int r0 = blockIdx.x * 64 + wave * 16;
    const int l15 = lane & 15, lg = lane >> 4;
    int arow = r0 + l15; if (arow >= NN) arow = NN - 1;   // clamp loads; stores guarded
    const int kbase = lg * 8;

    #pragma unroll
    for (int m = 0; m < 3; ++m) {
        f32x4 acc[8];
        #pragma unroll
        for (int nt = 0; nt < 8; ++nt) acc[nt] = (f32x4){0.f, 0.f, 0.f, 0.f};

        const ushort* __restrict__ wh = wt + (size_t)m * 2 * 16384;
        const ushort* __restrict__ wl = wh + 16384;
        #pragma unroll
        for (int kc = 0; kc < 4; ++kc) {
            const int ko = kc * 32 + kbase;
            bf16x8 ah = *(const bf16x8*)&xh[(size_t)arow * DD + ko];
            bf16x8 av = *(const bf16x8*)&xl[(size_t)arow * DD + ko];
            #pragma unroll
            for (int nt = 0; nt < 8; ++nt) {
                const int ncol = nt * 16 + l15;
                bf16x8 bh = *(const bf16x8*)&wh[(size_t)ncol * DD + ko];
                bf16x8 bv = *(const bf16x8*)&wl[(size_t)ncol * DD + ko];
                acc[nt] = __builtin_amdgcn_mfma_f32_16x16x32_bf16(ah, bh, acc[nt], 0, 0, 0);
                acc[nt] = __builtin_amdgcn_mfma_f32_16x16x32_bf16(ah, bv, acc[nt], 0, 0, 0);
                acc[nt] = __builtin_amdgcn_mfma_f32_16x16x32_bf16(av, bh, acc[nt], 0, 0, 0);
            }
        }

        // C/D layout: col = nt*16 + l15, row = r0 + lg*4 + r
        if (m < 2) {
            ushort* __restrict__ fb = (m == 0) ? fb0 : fb1;
            const float* __restrict__ alm = (m == 0) ? al0 : al1;
            const float* __restrict__ arm = (m == 0) ? ar0 : ar1;
            float pl[4][4], pr[4][4];
            #pragma unroll
            for (int r = 0; r < 4; ++r)
                #pragma unroll
                for (int h = 0; h < 4; ++h) { pl[r][h] = 0.f; pr[r][h] = 0.f; }

            #pragma unroll
            for (int nt = 0; nt < 8; ++nt) {
                const int col = nt * 16 + l15;
                const float wlv = alm[col], wrv = arm[col];
                #pragma unroll
                for (int r = 0; r < 4; ++r) {
                    float v = acc[nt][r];
                    pl[r][nt >> 1] += v * wlv;        // head = col>>5 = nt>>1
                    pr[r][nt >> 1] += v * wrv;
                    int row = r0 + lg * 4 + r;
                    if (row < NN) {
                        __hip_bfloat16 hb = __float2bfloat16(v);
                        fb[(size_t)row * DD + col] = *(ushort*)&hb;
                    }
                }
            }
            // head-segmented sums live across l15; butterfly-reduce the 16 lanes
            #pragma unroll
            for (int msk = 1; msk < 16; msk <<= 1)
                #pragma unroll
                for (int r = 0; r < 4; ++r)
                    #pragma unroll
                    for (int h = 0; h < 4; ++h) {
                        pl[r][h] += __shfl_xor(pl[r][h], msk);
                        pr[r][h] += __shfl_xor(pr[r][h], msk);
                    }
            float* __restrict__ elm = (m == 0) ? el0 : el1;
            float* __restrict__ erm = (m == 0) ? er0 : er1;
            if (l15 < 4) {
                const int h = l15;
                #pragma unroll
                for (int r = 0; r < 4; ++r) {
                    int row = r0 + lg * 4 + r;
                    if (row < NN) {
                        elm[(size_t)row * 4 + h] = pl[r][h];
                        erm[(size_t)row * 4 + h] = pr[r][h];
                    }
                }
            }
        } else {
            #pragma unroll
            for (int nt = 0; nt < 8; ++nt) {
                const int col = nt * 16 + l15;
                const float bv = bias[col];
                #pragma unroll
                for (int r = 0; r < 4; ++r) {
                    int row = r0 + lg * 4 + r;
                    if (row < NN)
                        out[(size_t)row * DD + col] = acc[nt][r] + bv;
                }
            }
        }
    }
}

// ---------------- CSR build: histogram ---------------------------------------
__global__ __launch_bounds__(256) void hist_kernel(
    const int* __restrict__ dst0, const int* __restrict__ dst1,
    int* __restrict__ deg0, int* __restrict__ deg1)
{
    int e = blockIdx.x * 256 + threadIdx.x;
    if (e < EE)               atomicAdd(&deg0[dst0[e]], 1);
    else if (e < 2 * EE)      atomicAdd(&deg1[dst1[e - EE]], 1);
}

// ---------------- CSR build: exclusive scan (one block per relation) ----------
__global__ __launch_bounds__(1024) void scan_kernel(
    const int* __restrict__ deg0, int* __restrict__ row0,
    const int* __restrict__ deg1, int* __restrict__ row1)
{
    const int* __restrict__ deg = blockIdx.x ? deg1 : deg0;
    int* __restrict__ row = blockIdx.x ? row1 : row0;
    __shared__ int wtot[16];
    __shared__ int carry_s;
    const int t = threadIdx.x;
    const int lane = t & 63, wave = t >> 6;
    if (t == 0) carry_s = 0;
    __syncthreads();
    for (int base = 0; base < NN; base += 1024) {
        int idx = base + t;
        int v = (idx < NN) ? deg[idx] : 0;
        int incl = v;
        #pragma unroll
        for (int off = 1; off < 64; off <<= 1) {
            int u = __shfl_up(incl, off);
            if (lane >= off) incl += u;
        }
        if (lane == 63) wtot[wave] = incl;
        __syncthreads();
        int carry = carry_s;
        int woff = 0;
        #pragma unroll
        for (int w = 0; w < 16; ++w) woff += (w < wave) ? wtot[w] : 0;
        if (idx < NN) row[idx] = carry + woff + incl - v;   // exclusive
        __syncthreads();
        if (t == 1023) carry_s = carry + woff + incl;
        __syncthreads();
    }
}

// ---------------- CSR build: scatter (row[d] becomes segment END) -------------
__global__ __launch_bounds__(256) void scatter_kernel(
    const int* __restrict__ src0, const int* __restrict__ dst0,
    int* __restrict__ row0, int* __restrict__ list0,
    const int* __restrict__ src1, const int* __restrict__ dst1,
    int* __restrict__ row1, int* __restrict__ list1)
{
    int e = blockIdx.x * 256 + threadIdx.x;
    if (e < EE) {
        int pos = atomicAdd(&row0[dst0[e]], 1);
        list0[pos] = src0[e];
    } else if (e < 2 * EE) {
        int i = e - EE;
        int pos = atomicAdd(&row1[dst1[i]], 1);
        list1[pos] = src1[i];
    }
}

// ---------------- aggregate: one wave per dst node, both relations ------------
__global__ __launch_bounds__(256) void agg_kernel(
    const int* __restrict__ row0, const int* __restrict__ list0,
    const float* __restrict__ el0, const float* __restrict__ er0,
    const int* __restrict__ row1, const int* __restrict__ list1,
    const float* __restrict__ el1, const float* __restrict__ er1,
    const ushort* __restrict__ fb0, const ushort* __restrict__ fb1,
    float* __restrict__ out)
{
    const int d = blockIdx.x * 4 + (threadIdx.x >> 6);
    const int lane = threadIdx.x & 63;
    if (d >= NN) return;

    const int s0 = d ? row0[d - 1] : 0, e0 = row0[d];
    const int s1 = d ? row1[d - 1] : 0, e1 = row1[d];

    const float4 erd0 = *(const float4*)&er0[(size_t)d * 4];
    const float4 erd1 = *(const float4*)&er1[(size_t)d * 4];

    float d0x = 0.f, d0y = 0.f, d0z = 0.f, d0w = 0.f;
    float d1x = 0.f, d1y = 0.f, d1z = 0.f, d1w = 0.f;
    for (int i = s0 + lane; i < e0; i += 64) {
        int s = list0[i];
        float4 l = *(const float4*)&el0[(size_t)s * 4];
        float v;
        v = l.x + erd0.x; d0x += __expf(v > 0.f ? v : NEG_SLOPE * v);
        v = l.y + erd0.y; d0y += __expf(v > 0.f ? v : NEG_SLOPE * v);
        v = l.z + erd0.z; d0z += __expf(v > 0.f ? v : NEG_SLOPE * v);
        v = l.w + erd0.w; d0w += __expf(v > 0.f ? v : NEG_SLOPE * v);
    }
    for (int i = s1 + lane; i < e1; i += 64) {
        int s = list1[i];
        float4 l = *(const float4*)&el1[(size_t)s * 4];
        float v;
        v = l.x + erd1.x; d1x += __expf(v > 0.f ? v : NEG_SLOPE * v);
        v = l.y + erd1.y; d1y += __expf(v > 0.f ? v : NEG_SLOPE * v);
        v = l.z + erd1.z; d1z += __expf(v > 0.f ? v : NEG_SLOPE * v);
        v = l.w + erd1.w; d1w += __expf(v > 0.f ? v : NEG_SLOPE * v);
    }
    #pragma unroll
    for (int m = 32; m; m >>= 1) {
        d0x += __shfl_xor(d0x, m); d0y += __shfl_xor(d0y, m);
        d0z += __shfl_xor(d0z, m); d0w += __shfl_xor(d0w, m);
        d1x += __shfl_xor(d1x, m); d1y += __shfl_xor(d1y, m);
        d1z += __shfl_xor(d1z, m); d1w += __shfl_xor(d1w, m);
    }

    const int h = lane >> 4;
    const int c = lane * 2;
    const float erh0 = (h == 0) ? erd0.x : (h == 1) ? erd0.y : (h == 2) ? erd0.z : erd0.w;
    const float erh1 = (h == 0) ? erd1.x : (h == 1) ? erd1.y : (h == 2) ? erd1.z : erd1.w;
    const float dh0  = (h == 0) ? d0x : (h == 1) ? d0y : (h == 2) ? d0z : d0w;
    const float dh1  = (h == 0) ? d1x : (h == 1) ? d1y : (h == 2) ? d1z : d1w;
    const float inv0 = (e0 > s0) ? 1.f / dh0 : 0.f;
    const float inv1 = (e1 > s1) ? 1.f / dh1 : 0.f;

    float accx = 0.f, accy = 0.f;
    for (int i = s0; i < e0; ++i) {
        int s = list0[i];
        float ev = el0[(size_t)s * 4 + h] + erh0;
        ev = ev > 0.f ? ev : NEG_SLOPE * ev;
        float a = __expf(ev) * inv0;
        ushort2 f = *(const ushort2*)&fb0[(size_t)s * DD + c];
        accx += a * bf2f(f.x); accy += a * bf2f(f.y);
    }
    for (int i = s1; i < e1; ++i) {
        int s = list1[i];
        float ev = el1[(size_t)s * 4 + h] + erh1;
        ev = ev > 0.f ? ev : NEG_SLOPE * ev;
        float a = __expf(ev) * inv1;
        ushort2 f = *(const ushort2*)&fb1[(size_t)s * DD + c];
        accx += a * bf2f(f.x); accy += a * bf2f(f.y);
    }

    float2 o = *(float2*)&out[(size_t)d * DD + c];
    o.x = fmaxf(o.x + accx, 0.f);
    o.y = fmaxf(o.y + accy, 0.f);
    *(float2*)&out[(size_t)d * DD + c] = o;
}

extern "C" void kernel_launch(void* const* d_in, const int* in_sizes, int n_in,
                              void* d_out, int out_size, void* d_ws, size_t ws_size,
                              hipStream_t stream)
{
    const float* x    = (const float*)d_in[0];
    const float* W0   = (const float*)d_in[1];
    const float* al0  = (const float*)d_in[2];
    const float* ar0  = (const float*)d_in[3];
    const float* W1   = (const float*)d_in[4];
    const float* al1  = (const float*)d_in[5];
    const float* ar1  = (const float*)d_in[6];
    const float* Wl   = (const float*)d_in[7];
    const float* bias = (const float*)d_in[8];
    const int* src0   = (const int*)d_in[9];
    const int* dst0   = (const int*)d_in[10];
    const int* src1   = (const int*)d_in[11];
    const int* dst1   = (const int*)d_in[12];
    float* out = (float*)d_out;

    // workspace layout
    ushort* wsu = (ushort*)d_ws;
    ushort* xh  = wsu;                          // N*128
    ushort* xl  = xh + (size_t)NN * DD;
    ushort* fb0 = xl + (size_t)NN * DD;
    ushort* fb1 = fb0 + (size_t)NN * DD;
    ushort* wt  = fb1 + (size_t)NN * DD;        // 3*2*128*128
    float* fbase = (float*)(wt + 3 * 2 * 128 * 128);
    float* el0  = fbase;
    float* er0  = el0 + (size_t)NN * HH;
    float* el1  = er0 + (size_t)NN * HH;
    float* er1  = el1 + (size_t)NN * HH;
    int* deg0   = (int*)(er1 + (size_t)NN * HH);
    int* deg1   = deg0 + NN;
    int* row0   = deg1 + NN;
    int* row1   = row0 + NN;
    int* list0  = row1 + NN;                    // E each
    int* list1  = list0 + EE;

    hipMemsetAsync(deg0, 0, (size_t)2 * NN * sizeof(int), stream);

    xcvt_kernel<<<dim3(NN * DD / 4 / 256 + 1), dim3(256), 0, stream>>>(x, xh, xl);
    wcvt_kernel<<<dim3(192), dim3(256), 0, stream>>>(W0, W1, Wl, wt);

    hist_kernel<<<dim3((2 * EE + 255) / 256), dim3(256), 0, stream>>>(
        dst0, dst1, deg0, deg1);
    scan_kernel<<<dim3(2), dim3(1024), 0, stream>>>(deg0, row0, deg1, row1);

    proj_kernel<<<dim3((NN + 63) / 64), dim3(256), 0, stream>>>(
        xh, xl, wt, al0, ar0, al1, ar1, bias,
        fb0, fb1, el0, er0, el1, er1, out);

    scatter_kernel<<<dim3((2 * EE + 255) / 256), dim3(256), 0, stream>>>(
        src0, dst0, row0, list0, src1, dst1, row1, list1);

    agg_kernel<<<dim3((NN + 3) / 4), dim3(256), 0, stream>>>(
        row0, list0, el0, er0, row1, list1, el1, er1, fb0, fb1, out);
}

// Round 4
// 429.422 us; speedup vs baseline: 4.3062x; 1.2689x over previous
//
#include <hip/hip_runtime.h>
#include <hip/hip_bf16.h>

#define NN 50000
#define EE 800000
#define DD 128
#define HH 4
#define NEG_SLOPE 0.2f

#define PADN 50176            // 98 * 512, padded node count for scan
#define NCH 98                // chunks of 512 per relation

typedef __attribute__((ext_vector_type(8))) short bf16x8;
typedef __attribute__((ext_vector_type(4))) float f32x4;

static __device__ __forceinline__ float bf2f(ushort u) {
    union { unsigned int ui; float f; } v; v.ui = ((unsigned int)u) << 16; return v.f;
}
static __device__ __forceinline__ void split1(float v, ushort& h, ushort& l) {
    __hip_bfloat16 hb = __float2bfloat16(v);
    float hf = __bfloat162float(hb);
    __hip_bfloat16 lb = __float2bfloat16(v - hf);
    h = *(ushort*)&hb; l = *(ushort*)&lb;
}

// ---------------- prep: xcvt (6250 blk) + wcvt (192 blk) + hist (6250 blk) ----
#define XB 6250
#define WB 192
#define HB 6250
__global__ __launch_bounds__(256) void prep_kernel(
    const float* __restrict__ x,
    const float* __restrict__ W0, const float* __restrict__ W1,
    const float* __restrict__ Wl,
    const int* __restrict__ dst0, const int* __restrict__ dst1,
    ushort* __restrict__ xh, ushort* __restrict__ xl, ushort* __restrict__ wt,
    int* __restrict__ deg0, int* __restrict__ deg1)
{
    const int b = blockIdx.x;
    if (b < XB) {                                  // x -> (hi, lo) bf16 split
        int i = b * 256 + threadIdx.x;             // float4 idx, exact 1.6M
        float4 v = ((const float4*)x)[i];
        ushort4 h, l;
        split1(v.x, h.x, l.x); split1(v.y, h.y, l.y);
        split1(v.z, h.z, l.z); split1(v.w, h.w, l.w);
        *(ushort4*)&xh[(size_t)i * 4] = h;
        *(ushort4*)&xl[(size_t)i * 4] = l;
    } else if (b < XB + WB) {                      // W -> W^T (hi,lo)
        int idx = (b - XB) * 256 + threadIdx.x;    // 0..49151
        int m = idx >> 14, e = idx & 16383;
        const float* W = (m == 0) ? W0 : (m == 1) ? W1 : Wl;
        int k = e >> 7, n = e & 127;
        ushort h, l; split1(W[e], h, l);
        wt[((size_t)m * 2 + 0) * 16384 + (size_t)n * 128 + k] = h;
        wt[((size_t)m * 2 + 1) * 16384 + (size_t)n * 128 + k] = l;
    } else {                                       // degree histogram
        int e = (b - XB - WB) * 256 + threadIdx.x; // 0..1599999 exact
        if (e < EE) atomicAdd(&deg0[dst0[e]], 1);
        else        atomicAdd(&deg1[dst1[e - EE]], 1);
    }
}

// ---------------- scan stage A: per-chunk sums (wave per 512-chunk) -----------
__global__ __launch_bounds__(256) void scanA_kernel(
    const int* __restrict__ deg0, const int* __restrict__ deg1,
    int* __restrict__ chunkSum)
{
    int chunk = blockIdx.x * 4 + (threadIdx.x >> 6);
    if (chunk >= 2 * NCH) return;
    int lane = threadIdx.x & 63;
    int rel = chunk >= NCH;
    int ci = chunk - rel * NCH;
    const int* __restrict__ deg = rel ? deg1 : deg0;
    const int4* p = (const int4*)&deg[ci * 512 + lane * 8];
    int4 a = p[0], q = p[1];
    int s = a.x + a.y + a.z + a.w + q.x + q.y + q.z + q.w;
    #pragma unroll
    for (int m = 32; m; m >>= 1) s += __shfl_xor(s, m);
    if (lane == 0) chunkSum[rel * 128 + ci] = s;
}

// ---------------- scan stage B: scan 128 chunk sums per relation --------------
__global__ __launch_bounds__(256) void scanB_kernel(
    const int* __restrict__ chunkSum, int* __restrict__ chunkBase)
{
    __shared__ int sm[256];
    int t = threadIdx.x;
    int idx = t & 127;
    int v = chunkSum[t];
    int val = v;
    sm[t] = v; __syncthreads();
    #pragma unroll
    for (int off = 1; off < 128; off <<= 1) {
        int u = (idx >= off) ? sm[t - off] : 0;
        __syncthreads();
        val += u; sm[t] = val;
        __syncthreads();
    }
    chunkBase[t] = val - v;                        // exclusive base
}

// ---------------- scan stage C: write exclusive row offsets -------------------
__global__ __launch_bounds__(256) void scanC_kernel(
    const int* __restrict__ deg0, const int* __restrict__ deg1,
    const int* __restrict__ chunkBase,
    int* __restrict__ row0, int* __restrict__ row1)
{
    int chunk = blockIdx.x * 4 + (threadIdx.x >> 6);
    if (chunk >= 2 * NCH) return;
    int lane = threadIdx.x & 63;
    int rel = chunk >= NCH;
    int ci = chunk - rel * NCH;
    const int* __restrict__ deg = rel ? deg1 : deg0;
    int* __restrict__ row = rel ? row1 : row0;
    const int base = ci * 512;
    const int4* p = (const int4*)&deg[base + lane * 8];
    int4 a = p[0], q = p[1];
    int lsum = a.x + a.y + a.z + a.w + q.x + q.y + q.z + q.w;
    int incl = lsum;
    #pragma unroll
    for (int off = 1; off < 64; off <<= 1) {
        int u = __shfl_up(incl, off);
        if (lane >= off) incl += u;
    }
    int r = incl - lsum + chunkBase[rel * 128 + ci];
    int4 o1, o2;
    o1.x = r; r += a.x;  o1.y = r; r += a.y;  o1.z = r; r += a.z;  o1.w = r; r += a.w;
    o2.x = r; r += q.x;  o2.y = r; r += q.y;  o2.z = r; r += q.z;  o2.w = r; r += q.w;
    ((int4*)&row[base + lane * 8])[0] = o1;
    ((int4*)&row[base + lane * 8])[1] = o2;
}

// ---------------- CSR scatter (row[d] becomes segment END) --------------------
__global__ __launch_bounds__(256) void scatter_kernel(
    const int* __restrict__ src0, const int* __restrict__ dst0,
    int* __restrict__ row0, int* __restrict__ list0,
    const int* __restrict__ src1, const int* __restrict__ dst1,
    int* __restrict__ row1, int* __restrict__ list1)
{
    int e = blockIdx.x * 256 + threadIdx.x;
    if (e < EE) {
        int pos = atomicAdd(&row0[dst0[e]], 1);
        list0[pos] = src0[e];
    } else if (e < 2 * EE) {
        int i = e - EE;
        int pos = atomicAdd(&row1[dst1[i]], 1);
        list1[pos] = src1[i];
    }
}

// ---------------- proj: MFMA, fused el/er + bias + bf16 feat ------------------
__global__ __launch_bounds__(256) void proj_kernel(
    const ushort* __restrict__ xh, const ushort* __restrict__ xl,
    const ushort* __restrict__ wt,
    const float* __restrict__ al0, const float* __restrict__ ar0,
    const float* __restrict__ al1, const float* __restrict__ ar1,
    const float* __restrict__ bias,
    ushort* __restrict__ fb0, ushort* __restrict__ fb1,
    float* __restrict__ el0, float* __restrict__ er0,
    float* __restrict__ el1, float* __restrict__ er1,
    float* __restrict__ out)
{
    const int lane = threadIdx.x & 63;
    const int wave = threadIdx.x >> 6;
    const int r0 = blockIdx.x * 64 + wave * 16;
    const int l15 = lane & 15, lg = lane >> 4;
    int arow = r0 + l15; if (arow >= NN) arow = NN - 1;
    const int kbase = lg * 8;

    #pragma unroll
    for (int m = 0; m < 3; ++m) {
        f32x4 acc[8];
        #pragma unroll
        for (int nt = 0; nt < 8; ++nt) acc[nt] = (f32x4){0.f, 0.f, 0.f, 0.f};

        const ushort* __restrict__ wh = wt + (size_t)m * 2 * 16384;
        const ushort* __restrict__ wl = wh + 16384;
        #pragma unroll
        for (int kc = 0; kc < 4; ++kc) {
            const int ko = kc * 32 + kbase;
            bf16x8 ah = *(const bf16x8*)&xh[(size_t)arow * DD + ko];
            bf16x8 av = *(const bf16x8*)&xl[(size_t)arow * DD + ko];
            #pragma unroll
            for (int nt = 0; nt < 8; ++nt) {
                const int ncol = nt * 16 + l15;
                bf16x8 bh = *(const bf16x8*)&wh[(size_t)ncol * DD + ko];
                bf16x8 bv = *(const bf16x8*)&wl[(size_t)ncol * DD + ko];
                acc[nt] = __builtin_amdgcn_mfma_f32_16x16x32_bf16(ah, bh, acc[nt], 0, 0, 0);
                acc[nt] = __builtin_amdgcn_mfma_f32_16x16x32_bf16(ah, bv, acc[nt], 0, 0, 0);
                acc[nt] = __builtin_amdgcn_mfma_f32_16x16x32_bf16(av, bh, acc[nt], 0, 0, 0);
            }
        }

        if (m < 2) {
            ushort* __restrict__ fb = (m == 0) ? fb0 : fb1;
            const float* __restrict__ alm = (m == 0) ? al0 : al1;
            const float* __restrict__ arm = (m == 0) ? ar0 : ar1;
            float pl[4][4], pr[4][4];
            #pragma unroll
            for (int r = 0; r < 4; ++r)
                #pragma unroll
                for (int h = 0; h < 4; ++h) { pl[r][h] = 0.f; pr[r][h] = 0.f; }

            #pragma unroll
            for (int nt = 0; nt < 8; ++nt) {
                const int col = nt * 16 + l15;
                const float wlv = alm[col], wrv = arm[col];
                #pragma unroll
                for (int r = 0; r < 4; ++r) {
                    float v = acc[nt][r];
                    pl[r][nt >> 1] += v * wlv;
                    pr[r][nt >> 1] += v * wrv;
                    int row = r0 + lg * 4 + r;
                    if (row < NN) {
                        __hip_bfloat16 hb = __float2bfloat16(v);
                        fb[(size_t)row * DD + col] = *(ushort*)&hb;
                    }
                }
            }
            #pragma unroll
            for (int msk = 1; msk < 16; msk <<= 1)
                #pragma unroll
                for (int r = 0; r < 4; ++r)
                    #pragma unroll
                    for (int h = 0; h < 4; ++h) {
                        pl[r][h] += __shfl_xor(pl[r][h], msk);
                        pr[r][h] += __shfl_xor(pr[r][h], msk);
                    }
            float* __restrict__ elm = (m == 0) ? el0 : el1;
            float* __restrict__ erm = (m == 0) ? er0 : er1;
            if (l15 < 4) {
                const int h = l15;
                #pragma unroll
                for (int r = 0; r < 4; ++r) {
                    int row = r0 + lg * 4 + r;
                    if (row < NN) {
                        elm[(size_t)row * 4 + h] = pl[r][h];
                        erm[(size_t)row * 4 + h] = pr[r][h];
                    }
                }
            }
        } else {
            #pragma unroll
            for (int nt = 0; nt < 8; ++nt) {
                const int col = nt * 16 + l15;
                const float bv = bias[col];
                #pragma unroll
                for (int r = 0; r < 4; ++r) {
                    int row = r0 + lg * 4 + r;
                    if (row < NN)
                        out[(size_t)row * DD + col] = acc[nt][r] + bv;
                }
            }
        }
    }
}

// ---------------- aggregate: wave per dst, single-pass, 2 edges in flight -----
__global__ __launch_bounds__(256) void agg_kernel(
    const int* __restrict__ row0, const int* __restrict__ list0,
    const float* __restrict__ el0, const float* __restrict__ er0,
    const int* __restrict__ row1, const int* __restrict__ list1,
    const float* __restrict__ el1, const float* __restrict__ er1,
    const ushort* __restrict__ fb0, const ushort* __restrict__ fb1,
    float* __restrict__ out)
{
    const int d = blockIdx.x * 4 + (threadIdx.x >> 6);
    const int lane = threadIdx.x & 63;
    if (d >= NN) return;
    const int half = lane >> 5;          // which edge of the in-flight pair
    const int l32 = lane & 31;
    const int c = l32 * 4;               // 4 output cols per lane
    const int h = l32 >> 3;              // head = col>>5

    float tot[4] = {0.f, 0.f, 0.f, 0.f};

    // ---- relation 0: U = sum w*feat, D = sum w; out += U/D ----
    {
        const int s0 = d ? row0[d - 1] : 0, e0 = row0[d];
        const float erh = er0[(size_t)d * 4 + h];
        float acc[4] = {0.f, 0.f, 0.f, 0.f};
        float den = 0.f;
        for (int i = s0 + half; i < e0; i += 2) {
            int s = list0[i];
            float ev = el0[(size_t)s * 4 + h] + erh;
            ev = ev > 0.f ? ev : NEG_SLOPE * ev;
            float w = __expf(ev);
            den += w;
            ushort4 f = *(const ushort4*)&fb0[(size_t)s * DD + c];
            acc[0] += w * bf2f(f.x); acc[1] += w * bf2f(f.y);
            acc[2] += w * bf2f(f.z); acc[3] += w * bf2f(f.w);
        }
        den += __shfl_xor(den, 32);
        #pragma unroll
        for (int q = 0; q < 4; ++q) acc[q] += __shfl_xor(acc[q], 32);
        if (e0 > s0) {
            float inv = 1.f / den;
            #pragma unroll
            for (int q = 0; q < 4; ++q) tot[q] += acc[q] * inv;
        }
    }
    // ---- relation 1 ----
    {
        const int s1 = d ? row1[d - 1] : 0, e1 = row1[d];
        const float erh = er1[(size_t)d * 4 + h];
        float acc[4] = {0.f, 0.f, 0.f, 0.f};
        float den = 0.f;
        for (int i = s1 + half; i < e1; i += 2) {
            int s = list1[i];
            float ev = el1[(size_t)s * 4 + h] + erh;
            ev = ev > 0.f ? ev : NEG_SLOPE * ev;
            float w = __expf(ev);
            den += w;
            ushort4 f = *(const ushort4*)&fb1[(size_t)s * DD + c];
            acc[0] += w * bf2f(f.x); acc[1] += w * bf2f(f.y);
            acc[2] += w * bf2f(f.z); acc[3] += w * bf2f(f.w);
        }
        den += __shfl_xor(den, 32);
        #pragma unroll
        for (int q = 0; q < 4; ++q) acc[q] += __shfl_xor(acc[q], 32);
        if (e1 > s1) {
            float inv = 1.f / den;
            #pragma unroll
            for (int q = 0; q < 4; ++q) tot[q] += acc[q] * inv;
        }
    }

    if (half == 0) {
        float4 o = *(float4*)&out[(size_t)d * DD + c];
        o.x = fmaxf(o.x + tot[0], 0.f);
        o.y = fmaxf(o.y + tot[1], 0.f);
        o.z = fmaxf(o.z + tot[2], 0.f);
        o.w = fmaxf(o.w + tot[3], 0.f);
        *(float4*)&out[(size_t)d * DD + c] = o;
    }
}

extern "C" void kernel_launch(void* const* d_in, const int* in_sizes, int n_in,
                              void* d_out, int out_size, void* d_ws, size_t ws_size,
                              hipStream_t stream)
{
    const float* x    = (const float*)d_in[0];
    const float* W0   = (const float*)d_in[1];
    const float* al0  = (const float*)d_in[2];
    const float* ar0  = (const float*)d_in[3];
    const float* W1   = (const float*)d_in[4];
    const float* al1  = (const float*)d_in[5];
    const float* ar1  = (const float*)d_in[6];
    const float* Wl   = (const float*)d_in[7];
    const float* bias = (const float*)d_in[8];
    const int* src0   = (const int*)d_in[9];
    const int* dst0   = (const int*)d_in[10];
    const int* src1   = (const int*)d_in[11];
    const int* dst1   = (const int*)d_in[12];
    float* out = (float*)d_out;

    // workspace layout
    ushort* wsu = (ushort*)d_ws;
    ushort* xh  = wsu;                          // N*128
    ushort* xl  = xh + (size_t)NN * DD;
    ushort* fb0 = xl + (size_t)NN * DD;
    ushort* fb1 = fb0 + (size_t)NN * DD;
    ushort* wt  = fb1 + (size_t)NN * DD;        // 3*2*16384
    float* fbase = (float*)(wt + 3 * 2 * 16384);
    float* el0  = fbase;
    float* er0  = el0 + (size_t)NN * HH;
    float* el1  = er0 + (size_t)NN * HH;
    float* er1  = el1 + (size_t)NN * HH;
    int* deg0   = (int*)(er1 + (size_t)NN * HH);
    int* deg1   = deg0 + PADN;
    int* chunkSum  = deg1 + PADN;               // 2*128
    int* chunkBase = chunkSum + 256;            // 2*128
    int* row0   = chunkBase + 256;
    int* row1   = row0 + PADN;
    int* list0  = row1 + PADN;                  // E each
    int* list1  = list0 + EE;

    // zero deg (incl. pad) + chunkSum + chunkBase
    hipMemsetAsync(deg0, 0, ((size_t)2 * PADN + 512) * sizeof(int), stream);

    prep_kernel<<<dim3(XB + WB + HB), dim3(256), 0, stream>>>(
        x, W0, W1, Wl, dst0, dst1, xh, xl, wt, deg0, deg1);

    scanA_kernel<<<dim3((2 * NCH + 3) / 4), dim3(256), 0, stream>>>(
        deg0, deg1, chunkSum);
    scanB_kernel<<<dim3(1), dim3(256), 0, stream>>>(chunkSum, chunkBase);
    scanC_kernel<<<dim3((2 * NCH + 3) / 4), dim3(256), 0, stream>>>(
        deg0, deg1, chunkBase, row0, row1);

    scatter_kernel<<<dim3((2 * EE + 255) / 256), dim3(256), 0, stream>>>(
        src0, dst0, row0, list0, src1, dst1, row1, list1);

    proj_kernel<<<dim3((NN + 63) / 64), dim3(256), 0, stream>>>(
        xh, xl, wt, al0, ar0, al1, ar1, bias,
        fb0, fb1, el0, er0, el1, er1, out);

    agg_kernel<<<dim3((NN + 3) / 4), dim3(256), 0, stream>>>(
        row0, list0, el0, er0, row1, list1, el1, er1, fb0, fb1, out);
}

// Round 5
// 277.154 us; speedup vs baseline: 6.6720x; 1.5494x over previous
//
#include <hip/hip_runtime.h>
#include <hip/hip_bf16.h>

#define NN 50000
#define EE 800000
#define DD 128
#define HH 4
#define NEG_SLOPE 0.2f

#define BSH 9                 // bucket = dst >> 9 (512 dsts)
#define NBUCK 98              // ceil(50000/512)
#define CH 8192               // edges per chunk
#define NBLK 98               // ceil(800000/8192)
#define NSEG (2 * NBUCK * NBLK)   // 19208 flat scan cells

typedef __attribute__((ext_vector_type(8))) short bf16x8;
typedef __attribute__((ext_vector_type(4))) float f32x4;
typedef __attribute__((ext_vector_type(8))) unsigned short ushrt8;

static __device__ __forceinline__ float bf2f(ushort u) {
    union { unsigned int ui; float f; } v; v.ui = ((unsigned int)u) << 16; return v.f;
}
static __device__ __forceinline__ void split1(float v, ushort& h, ushort& l) {
    __hip_bfloat16 hb = __float2bfloat16(v);
    float hf = __bfloat162float(hb);
    __hip_bfloat16 lb = __float2bfloat16(v - hf);
    h = *(ushort*)&hb; l = *(ushort*)&lb;
}

// ---------------- prep: xcvt (6250) + wcvt (192) + bucket-hist (196) ----------
#define XB 6250
#define WB 192
__global__ __launch_bounds__(256) void prep_kernel(
    const float* __restrict__ x,
    const float* __restrict__ W0, const float* __restrict__ W1,
    const float* __restrict__ Wl,
    const int* __restrict__ dst0, const int* __restrict__ dst1,
    ushort* __restrict__ xh, ushort* __restrict__ xl, ushort* __restrict__ wt,
    int* __restrict__ hist)
{
    const int b = blockIdx.x;
    const int t = threadIdx.x;
    if (b < XB) {                                  // x -> (hi, lo) bf16 split
        int i = b * 256 + t;                       // float4 idx, exact 1.6M
        float4 v = ((const float4*)x)[i];
        ushort4 h, l;
        split1(v.x, h.x, l.x); split1(v.y, h.y, l.y);
        split1(v.z, h.z, l.z); split1(v.w, h.w, l.w);
        *(ushort4*)&xh[(size_t)i * 4] = h;
        *(ushort4*)&xl[(size_t)i * 4] = l;
    } else if (b < XB + WB) {                      // W -> W^T (hi,lo)
        int idx = (b - XB) * 256 + t;              // 0..49151
        int m = idx >> 14, e = idx & 16383;
        const float* W = (m == 0) ? W0 : (m == 1) ? W1 : Wl;
        int k = e >> 7, n = e & 127;
        ushort h, l; split1(W[e], h, l);
        wt[((size_t)m * 2 + 0) * 16384 + (size_t)n * 128 + k] = h;
        wt[((size_t)m * 2 + 1) * 16384 + (size_t)n * 128 + k] = l;
    } else {                                       // per-chunk bucket histogram
        __shared__ int cnt[NBUCK];
        int hb = b - XB - WB;                      // 0..195
        int rel = hb >= NBLK;
        int ci = hb - rel * NBLK;
        const int* __restrict__ dstA = rel ? dst1 : dst0;
        if (t < NBUCK) cnt[t] = 0;
        __syncthreads();
        int lo = ci * CH, hi = min(lo + CH, EE);
        for (int i = lo + t; i < hi; i += 256)
            atomicAdd(&cnt[dstA[i] >> BSH], 1);
        __syncthreads();
        if (t < NBUCK)
            hist[((rel * NBUCK) + t) * NBLK + ci] = cnt[t];
    }
}

// ---------------- flat exclusive scan of hist -> base -------------------------
__global__ __launch_bounds__(256) void scan_kernel(
    const int* __restrict__ hist, int* __restrict__ base)
{
    __shared__ int wq[4];
    const int t = threadIdx.x;
    const int lane = t & 63, wv = t >> 6;
    const int st = t * 76;
    const int en = min(st + 76, NSEG);
    int sum = 0;
    for (int i = st; i < en; ++i) sum += hist[i];
    int incl = sum;
    #pragma unroll
    for (int off = 1; off < 64; off <<= 1) {
        int u = __shfl_up(incl, off);
        if (lane >= off) incl += u;
    }
    if (lane == 63) wq[wv] = incl;
    __syncthreads();
    int woff = 0;
    #pragma unroll
    for (int w = 0; w < 4; ++w) woff += (w < wv) ? wq[w] : 0;
    int run = woff + incl - sum;                   // exclusive prefix
    for (int i = st; i < en; ++i) { base[i] = run; run += hist[i]; }
}

// ---------------- scatter edges into bucket-contiguous runs -------------------
__global__ __launch_bounds__(256) void bucket_kernel(
    const int* __restrict__ src0, const int* __restrict__ dst0,
    const int* __restrict__ src1, const int* __restrict__ dst1,
    const int* __restrict__ base, unsigned int* __restrict__ pk)
{
    __shared__ int cnt[NBUCK];
    __shared__ int bs[NBUCK];
    const int hb = blockIdx.x;
    const int t = threadIdx.x;
    const int rel = hb >= NBLK;
    const int ci = hb - rel * NBLK;
    const int* __restrict__ srcA = rel ? src1 : src0;
    const int* __restrict__ dstA = rel ? dst1 : dst0;
    if (t < NBUCK) {
        cnt[t] = 0;
        bs[t] = base[((rel * NBUCK) + t) * NBLK + ci];
    }
    __syncthreads();
    int lo = ci * CH, hi = min(lo + CH, EE);
    for (int i = lo + t; i < hi; i += 256) {
        int dd = dstA[i], ss = srcA[i];
        int bk = dd >> BSH;
        int rk = atomicAdd(&cnt[bk], 1);
        pk[bs[bk] + rk] = (unsigned int)ss | ((unsigned int)(dd & 511) << 17);
    }
}

// ---------------- per-bucket counting sort -> CSR row + list ------------------
__global__ __launch_bounds__(256) void sort_kernel(
    const unsigned int* __restrict__ pk, const int* __restrict__ base,
    int* __restrict__ row0, int* __restrict__ row1, int* __restrict__ list)
{
    __shared__ int cnt[512];
    __shared__ int offs[512];
    __shared__ int wq[4];
    const int hb = blockIdx.x;
    const int t = threadIdx.x;
    const int lane = t & 63, wv = t >> 6;
    const int rel = hb >= NBUCK;
    const int bk = hb - rel * NBUCK;

    const int fs = base[((rel * NBUCK) + bk) * NBLK];
    const int fe = (rel == 1 && bk == NBUCK - 1) ? 2 * EE
                 : base[((rel * NBUCK) + bk + 1) * NBLK];

    cnt[t] = 0; cnt[t + 256] = 0;
    __syncthreads();
    for (int i = fs + t; i < fe; i += 256)
        atomicAdd(&cnt[pk[i] >> 17], 1);
    __syncthreads();

    // exclusive scan of 512 counts (pair per thread)
    int a = cnt[2 * t], bvl = cnt[2 * t + 1];
    int ps = a + bvl;
    int incl = ps;
    #pragma unroll
    for (int off = 1; off < 64; off <<= 1) {
        int u = __shfl_up(incl, off);
        if (lane >= off) incl += u;
    }
    if (lane == 63) wq[wv] = incl;
    __syncthreads();
    int woff = 0;
    #pragma unroll
    for (int w = 0; w < 4; ++w) woff += (w < wv) ? wq[w] : 0;
    int excl = woff + incl - ps;
    offs[2 * t] = excl;
    offs[2 * t + 1] = excl + a;
    __syncthreads();

    // CSR row ends (coalesced), before offs is mutated
    int* __restrict__ row = rel ? row1 : row0;
    const int fsLocal = fs - (rel ? EE : 0);
    const int d0 = bk << BSH;
    for (int j = t; j < 512; j += 256) {
        int d = d0 + j;
        if (d < NN) row[d] = fsLocal + offs[j] + cnt[j];
    }
    __syncthreads();

    // scatter src into final sorted list (writes confined to this bucket run)
    for (int i = fs + t; i < fe; i += 256) {
        unsigned int u = pk[i];
        int ld = u >> 17;
        int p = atomicAdd(&offs[ld], 1);
        list[fs + p] = (int)(u & 0x1FFFF);
    }
}

// ---------------- proj: MFMA, fused el/er + bias + bf16 feat ------------------
__global__ __launch_bounds__(256) void proj_kernel(
    const ushort* __restrict__ xh, const ushort* __restrict__ xl,
    const ushort* __restrict__ wt,
    const float* __restrict__ al0, const float* __restrict__ ar0,
    const float* __restrict__ al1, const float* __restrict__ ar1,
    const float* __restrict__ bias,
    ushort* __restrict__ fb0, ushort* __restrict__ fb1,
    float* __restrict__ el0, float* __restrict__ er0,
    float* __restrict__ el1, float* __restrict__ er1,
    float* __restrict__ out)
{
    const int lane = threadIdx.x & 63;
    const int wave = threadIdx.x >> 6;
    const int r0 = blockIdx.x * 64 + wave * 16;
    const int l15 = lane & 15, lg = lane >> 4;
    int arow = r0 + l15; if (arow >= NN) arow = NN - 1;
    const int kbase = lg * 8;

    #pragma unroll
    for (int m = 0; m < 3; ++m) {
        f32x4 acc[8];
        #pragma unroll
        for (int nt = 0; nt < 8; ++nt) acc[nt] = (f32x4){0.f, 0.f, 0.f, 0.f};

        const ushort* __restrict__ wh = wt + (size_t)m * 2 * 16384;
        const ushort* __restrict__ wl = wh + 16384;
        #pragma unroll
        for (int kc = 0; kc < 4; ++kc) {
            const int ko = kc * 32 + kbase;
            bf16x8 ah = *(const bf16x8*)&xh[(size_t)arow * DD + ko];
            bf16x8 av = *(const bf16x8*)&xl[(size_t)arow * DD + ko];
            #pragma unroll
            for (int nt = 0; nt < 8; ++nt) {
                const int ncol = nt * 16 + l15;
                bf16x8 bh = *(const bf16x8*)&wh[(size_t)ncol * DD + ko];
                bf16x8 bv = *(const bf16x8*)&wl[(size_t)ncol * DD + ko];
                acc[nt] = __builtin_amdgcn_mfma_f32_16x16x32_bf16(ah, bh, acc[nt], 0, 0, 0);
                acc[nt] = __builtin_amdgcn_mfma_f32_16x16x32_bf16(ah, bv, acc[nt], 0, 0, 0);
                acc[nt] = __builtin_amdgcn_mfma_f32_16x16x32_bf16(av, bh, acc[nt], 0, 0, 0);
            }
        }

        if (m < 2) {
            ushort* __restrict__ fb = (m == 0) ? fb0 : fb1;
            const float* __restrict__ alm = (m == 0) ? al0 : al1;
            const float* __restrict__ arm = (m == 0) ? ar0 : ar1;
            float pl[4][4], pr[4][4];
            #pragma unroll
            for (int r = 0; r < 4; ++r)
                #pragma unroll
                for (int h = 0; h < 4; ++h) { pl[r][h] = 0.f; pr[r][h] = 0.f; }

            #pragma unroll
            for (int nt = 0; nt < 8; ++nt) {
                const int col = nt * 16 + l15;
                const float wlv = alm[col], wrv = arm[col];
                #pragma unroll
                for (int r = 0; r < 4; ++r) {
                    float v = acc[nt][r];
                    pl[r][nt >> 1] += v * wlv;
                    pr[r][nt >> 1] += v * wrv;
                    int row = r0 + lg * 4 + r;
                    if (row < NN) {
                        __hip_bfloat16 hb = __float2bfloat16(v);
                        fb[(size_t)row * DD + col] = *(ushort*)&hb;
                    }
                }
            }
            #pragma unroll
            for (int msk = 1; msk < 16; msk <<= 1)
                #pragma unroll
                for (int r = 0; r < 4; ++r)
                    #pragma unroll
                    for (int h = 0; h < 4; ++h) {
                        pl[r][h] += __shfl_xor(pl[r][h], msk);
                        pr[r][h] += __shfl_xor(pr[r][h], msk);
                    }
            float* __restrict__ elm = (m == 0) ? el0 : el1;
            float* __restrict__ erm = (m == 0) ? er0 : er1;
            if (l15 < 4) {
                const int h = l15;
                #pragma unroll
                for (int r = 0; r < 4; ++r) {
                    int row = r0 + lg * 4 + r;
                    if (row < NN) {
                        elm[(size_t)row * 4 + h] = pl[r][h];
                        erm[(size_t)row * 4 + h] = pr[r][h];
                    }
                }
            }
        } else {
            #pragma unroll
            for (int nt = 0; nt < 8; ++nt) {
                const int col = nt * 16 + l15;
                const float bv = bias[col];
                #pragma unroll
                for (int r = 0; r < 4; ++r) {
                    int row = r0 + lg * 4 + r;
                    if (row < NN)
                        out[(size_t)row * DD + col] = acc[nt][r] + bv;
                }
            }
        }
    }
}

// ---------------- aggregate: wave per dst, 4 edges in flight ------------------
__global__ __launch_bounds__(256) void agg_kernel(
    const int* __restrict__ row0, const int* __restrict__ list0,
    const float* __restrict__ el0, const float* __restrict__ er0,
    const int* __restrict__ row1, const int* __restrict__ list1,
    const float* __restrict__ el1, const float* __restrict__ er1,
    const ushort* __restrict__ fb0, const ushort* __restrict__ fb1,
    float* __restrict__ out)
{
    const int d = blockIdx.x * 4 + (threadIdx.x >> 6);
    const int lane = threadIdx.x & 63;
    if (d >= NN) return;
    const int g = lane >> 4;             // which of 4 in-flight edges
    const int l16 = lane & 15;
    const int c = l16 * 8;               // 8 output cols per lane
    const int h = l16 >> 2;              // head = col>>5

    float tot[8] = {0.f, 0.f, 0.f, 0.f, 0.f, 0.f, 0.f, 0.f};

    #pragma unroll
    for (int rel = 0; rel < 2; ++rel) {
        const int* __restrict__ rowA = rel ? row1 : row0;
        const int* __restrict__ lst  = rel ? list1 : list0;
        const float* __restrict__ elA = rel ? el1 : el0;
        const float* __restrict__ erA = rel ? er1 : er0;
        const ushort* __restrict__ fbA = rel ? fb1 : fb0;

        const int s0 = d ? rowA[d - 1] : 0, e0 = rowA[d];
        const float erh = erA[(size_t)d * 4 + h];
        float acc[8] = {0.f, 0.f, 0.f, 0.f, 0.f, 0.f, 0.f, 0.f};
        float den = 0.f;
        for (int i = s0 + g; i < e0; i += 4) {
            int s = lst[i];
            float ev = elA[(size_t)s * 4 + h] + erh;
            ev = ev > 0.f ? ev : NEG_SLOPE * ev;
            float w = __expf(ev);
            den += w;
            ushrt8 f = *(const ushrt8*)&fbA[(size_t)s * DD + c];
            #pragma unroll
            for (int q = 0; q < 8; ++q) acc[q] += w * bf2f(f[q]);
        }
        den += __shfl_xor(den, 16); den += __shfl_xor(den, 32);
        #pragma unroll
        for (int q = 0; q < 8; ++q) {
            acc[q] += __shfl_xor(acc[q], 16);
            acc[q] += __shfl_xor(acc[q], 32);
        }
        if (e0 > s0) {
            float inv = 1.f / den;
            #pragma unroll
            for (int q = 0; q < 8; ++q) tot[q] += acc[q] * inv;
        }
    }

    if (g == 0) {
        float4 o1 = *(float4*)&out[(size_t)d * DD + c];
        float4 o2 = *(float4*)&out[(size_t)d * DD + c + 4];
        o1.x = fmaxf(o1.x + tot[0], 0.f); o1.y = fmaxf(o1.y + tot[1], 0.f);
        o1.z = fmaxf(o1.z + tot[2], 0.f); o1.w = fmaxf(o1.w + tot[3], 0.f);
        o2.x = fmaxf(o2.x + tot[4], 0.f); o2.y = fmaxf(o2.y + tot[5], 0.f);
        o2.z = fmaxf(o2.z + tot[6], 0.f); o2.w = fmaxf(o2.w + tot[7], 0.f);
        *(float4*)&out[(size_t)d * DD + c] = o1;
        *(float4*)&out[(size_t)d * DD + c + 4] = o2;
    }
}

extern "C" void kernel_launch(void* const* d_in, const int* in_sizes, int n_in,
                              void* d_out, int out_size, void* d_ws, size_t ws_size,
                              hipStream_t stream)
{
    const float* x    = (const float*)d_in[0];
    const float* W0   = (const float*)d_in[1];
    const float* al0  = (const float*)d_in[2];
    const float* ar0  = (const float*)d_in[3];
    const float* W1   = (const float*)d_in[4];
    const float* al1  = (const float*)d_in[5];
    const float* ar1  = (const float*)d_in[6];
    const float* Wl   = (const float*)d_in[7];
    const float* bias = (const float*)d_in[8];
    const int* src0   = (const int*)d_in[9];
    const int* dst0   = (const int*)d_in[10];
    const int* src1   = (const int*)d_in[11];
    const int* dst1   = (const int*)d_in[12];
    float* out = (float*)d_out;

    // workspace layout
    ushort* wsu = (ushort*)d_ws;
    ushort* xh  = wsu;                          // N*128
    ushort* xl  = xh + (size_t)NN * DD;
    ushort* fb0 = xl + (size_t)NN * DD;
    ushort* fb1 = fb0 + (size_t)NN * DD;
    ushort* wt  = fb1 + (size_t)NN * DD;        // 3*2*16384
    float* fbase = (float*)(wt + 3 * 2 * 16384);
    float* el0  = fbase;
    float* er0  = el0 + (size_t)NN * HH;
    float* el1  = er0 + (size_t)NN * HH;
    float* er1  = el1 + (size_t)NN * HH;
    int* hist   = (int*)(er1 + (size_t)NN * HH);
    int* base   = hist + NSEG;
    int* row0   = base + NSEG;
    int* row1   = row0 + NN;
    unsigned int* pk = (unsigned int*)(row1 + NN);   // 2*E
    int* list   = (int*)(pk + (size_t)2 * EE);       // 2*E
    int* list0  = list;
    int* list1  = list + EE;

    prep_kernel<<<dim3(XB + WB + 2 * NBLK), dim3(256), 0, stream>>>(
        x, W0, W1, Wl, dst0, dst1, xh, xl, wt, hist);

    scan_kernel<<<dim3(1), dim3(256), 0, stream>>>(hist, base);

    bucket_kernel<<<dim3(2 * NBLK), dim3(256), 0, stream>>>(
        src0, dst0, src1, dst1, base, pk);

    sort_kernel<<<dim3(2 * NBUCK), dim3(256), 0, stream>>>(
        pk, base, row0, row1, list);

    proj_kernel<<<dim3((NN + 63) / 64), dim3(256), 0, stream>>>(
        xh, xl, wt, al0, ar0, al1, ar1, bias,
        fb0, fb1, el0, er0, el1, er1, out);

    agg_kernel<<<dim3((NN + 3) / 4), dim3(256), 0, stream>>>(
        row0, list0, el0, er0, row1, list1, el1, er1, fb0, fb1, out);
}

// Round 6
// 223.777 us; speedup vs baseline: 8.2635x; 1.2385x over previous
//
#include <hip/hip_runtime.h>
#include <hip/hip_bf16.h>

#define NN 50000
#define EE 800000
#define DD 128
#define HH 4
#define NEG_SLOPE 0.2f

#define BSH 9                 // bucket = dst >> 9 (512 dsts)
#define NBUCK 98              // ceil(50000/512)
#define CH 8192               // edges per chunk
#define NBLK 98               // ceil(800000/8192)
#define NSEG (2 * NBUCK * NBLK)   // 19208 flat scan cells

typedef __attribute__((ext_vector_type(8))) short bf16x8;
typedef __attribute__((ext_vector_type(4))) float f32x4;
typedef __attribute__((ext_vector_type(8))) unsigned short ushrt8;

static __device__ __forceinline__ float bf2f(ushort u) {
    union { unsigned int ui; float f; } v; v.ui = ((unsigned int)u) << 16; return v.f;
}
static __device__ __forceinline__ void split1(float v, ushort& h, ushort& l) {
    __hip_bfloat16 hb = __float2bfloat16(v);
    float hf = __bfloat162float(hb);
    __hip_bfloat16 lb = __float2bfloat16(v - hf);
    h = *(ushort*)&hb; l = *(ushort*)&lb;
}

// ---------------- prep: xcvt (6250) + wcvt (192) + bucket-hist (196) ----------
// wt layout: 12 chunks (m*4+kc) of 16KB: [n=128][slot'=8][8 ushorts],
// slot = hl*4 + kin8, slot' = slot ^ (n&7)  -- swizzle baked in for LDS.
#define XB 6250
#define WB 192
__global__ __launch_bounds__(256) void prep_kernel(
    const float* __restrict__ x,
    const float* __restrict__ W0, const float* __restrict__ W1,
    const float* __restrict__ Wl,
    const int* __restrict__ dst0, const int* __restrict__ dst1,
    ushort* __restrict__ xh, ushort* __restrict__ xl, ushort* __restrict__ wt,
    int* __restrict__ hist)
{
    const int b = blockIdx.x;
    const int t = threadIdx.x;
    if (b < XB) {                                  // x -> (hi, lo) bf16 split
        int i = b * 256 + t;                       // float4 idx, exact 1.6M
        float4 v = ((const float4*)x)[i];
        ushort4 h, l;
        split1(v.x, h.x, l.x); split1(v.y, h.y, l.y);
        split1(v.z, h.z, l.z); split1(v.w, h.w, l.w);
        *(ushort4*)&xh[(size_t)i * 4] = h;
        *(ushort4*)&xl[(size_t)i * 4] = l;
    } else if (b < XB + WB) {                      // W -> pre-swizzled chunks
        int idx = (b - XB) * 256 + t;              // 0..49151
        int m = idx >> 14, e = idx & 16383;
        const float* W = (m == 0) ? W0 : (m == 1) ? W1 : Wl;
        int k = e >> 7, n = e & 127;               // W[k][n]
        ushort h, l; split1(W[e], h, l);
        int q = m * 4 + (k >> 5);
        int kin8 = (k >> 3) & 3, ke = k & 7;
        int sw = n & 7;
        size_t base = (size_t)q * 8192 + n * 64;
        wt[base + (((0 | kin8) ^ sw) << 3) + ke] = h;
        wt[base + (((4 | kin8) ^ sw) << 3) + ke] = l;
    } else {                                       // per-chunk bucket histogram
        __shared__ int cnt[NBUCK];
        int hb = b - XB - WB;                      // 0..195
        int rel = hb >= NBLK;
        int ci = hb - rel * NBLK;
        const int* __restrict__ dstA = rel ? dst1 : dst0;
        if (t < NBUCK) cnt[t] = 0;
        __syncthreads();
        int lo = ci * CH, hi = min(lo + CH, EE);
        for (int i = lo + t; i < hi; i += 256)
            atomicAdd(&cnt[dstA[i] >> BSH], 1);
        __syncthreads();
        if (t < NBUCK)
            hist[((rel * NBUCK) + t) * NBLK + ci] = cnt[t];
    }
}

// ---------------- flat exclusive scan of hist -> base -------------------------
__global__ __launch_bounds__(256) void scan_kernel(
    const int* __restrict__ hist, int* __restrict__ base)
{
    __shared__ int wq[4];
    const int t = threadIdx.x;
    const int lane = t & 63, wv = t >> 6;
    const int st = t * 76;
    const int en = min(st + 76, NSEG);
    int sum = 0;
    for (int i = st; i < en; ++i) sum += hist[i];
    int incl = sum;
    #pragma unroll
    for (int off = 1; off < 64; off <<= 1) {
        int u = __shfl_up(incl, off);
        if (lane >= off) incl += u;
    }
    if (lane == 63) wq[wv] = incl;
    __syncthreads();
    int woff = 0;
    #pragma unroll
    for (int w = 0; w < 4; ++w) woff += (w < wv) ? wq[w] : 0;
    int run = woff + incl - sum;                   // exclusive prefix
    for (int i = st; i < en; ++i) { base[i] = run; run += hist[i]; }
}

// ---------------- scatter edges into bucket-contiguous runs -------------------
__global__ __launch_bounds__(256) void bucket_kernel(
    const int* __restrict__ src0, const int* __restrict__ dst0,
    const int* __restrict__ src1, const int* __restrict__ dst1,
    const int* __restrict__ base, unsigned int* __restrict__ pk)
{
    __shared__ int cnt[NBUCK];
    __shared__ int bs[NBUCK];
    const int hb = blockIdx.x;
    const int t = threadIdx.x;
    const int rel = hb >= NBLK;
    const int ci = hb - rel * NBLK;
    const int* __restrict__ srcA = rel ? src1 : src0;
    const int* __restrict__ dstA = rel ? dst1 : dst0;
    if (t < NBUCK) {
        cnt[t] = 0;
        bs[t] = base[((rel * NBUCK) + t) * NBLK + ci];
    }
    __syncthreads();
    int lo = ci * CH, hi = min(lo + CH, EE);
    for (int i = lo + t; i < hi; i += 256) {
        int dd = dstA[i], ss = srcA[i];
        int bk = dd >> BSH;
        int rk = atomicAdd(&cnt[bk], 1);
        pk[bs[bk] + rk] = (unsigned int)ss | ((unsigned int)(dd & 511) << 17);
    }
}

// ---------------- per-bucket counting sort -> CSR row + list ------------------
__global__ __launch_bounds__(256) void sort_kernel(
    const unsigned int* __restrict__ pk, const int* __restrict__ base,
    int* __restrict__ row0, int* __restrict__ row1, int* __restrict__ list)
{
    __shared__ int cnt[512];
    __shared__ int offs[512];
    __shared__ int wq[4];
    const int hb = blockIdx.x;
    const int t = threadIdx.x;
    const int lane = t & 63, wv = t >> 6;
    const int rel = hb >= NBUCK;
    const int bk = hb - rel * NBUCK;

    const int fs = base[((rel * NBUCK) + bk) * NBLK];
    const int fe = (rel == 1 && bk == NBUCK - 1) ? 2 * EE
                 : base[((rel * NBUCK) + bk + 1) * NBLK];

    cnt[t] = 0; cnt[t + 256] = 0;
    __syncthreads();
    for (int i = fs + t; i < fe; i += 256)
        atomicAdd(&cnt[pk[i] >> 17], 1);
    __syncthreads();

    int a = cnt[2 * t], bvl = cnt[2 * t + 1];
    int ps = a + bvl;
    int incl = ps;
    #pragma unroll
    for (int off = 1; off < 64; off <<= 1) {
        int u = __shfl_up(incl, off);
        if (lane >= off) incl += u;
    }
    if (lane == 63) wq[wv] = incl;
    __syncthreads();
    int woff = 0;
    #pragma unroll
    for (int w = 0; w < 4; ++w) woff += (w < wv) ? wq[w] : 0;
    int excl = woff + incl - ps;
    offs[2 * t] = excl;
    offs[2 * t + 1] = excl + a;
    __syncthreads();

    int* __restrict__ row = rel ? row1 : row0;
    const int fsLocal = fs - (rel ? EE : 0);
    const int d0 = bk << BSH;
    for (int j = t; j < 512; j += 256) {
        int d = d0 + j;
        if (d < NN) row[d] = fsLocal + offs[j] + cnt[j];
    }
    __syncthreads();

    for (int i = fs + t; i < fe; i += 256) {
        unsigned int u = pk[i];
        int ld = u >> 17;
        int p = atomicAdd(&offs[ld], 1);
        list[fs + p] = (int)(u & 0x1FFFF);
    }
}

// ---------------- proj: LDS-staged W, double-buffered, 128 rows/block ---------
__global__ __launch_bounds__(256) void proj_kernel(
    const ushort* __restrict__ xh, const ushort* __restrict__ xl,
    const ushort* __restrict__ wt,
    const float* __restrict__ al0, const float* __restrict__ ar0,
    const float* __restrict__ al1, const float* __restrict__ ar1,
    const float* __restrict__ bias,
    ushort* __restrict__ fb0, ushort* __restrict__ fb1,
    float* __restrict__ el0, float* __restrict__ er0,
    float* __restrict__ el1, float* __restrict__ er1,
    float* __restrict__ out)
{
    __shared__ ushort lds[2][8192];               // 2 x 16KB W chunks
    const int t = threadIdx.x;
    const int lane = t & 63, wave = t >> 6;
    const int l15 = lane & 15, lg = lane >> 4;
    const int rb = blockIdx.x * 128 + wave * 32;

    int ra0 = rb + l15;      if (ra0 > NN - 1) ra0 = NN - 1;
    int ra1 = rb + 16 + l15; if (ra1 > NN - 1) ra1 = NN - 1;
    const int kb = lg * 8;

    // A fragments in registers, reused across all 3 matrices
    bf16x8 Ah0[4], Av0[4], Ah1[4], Av1[4];
    #pragma unroll
    for (int kc = 0; kc < 4; ++kc) {
        Ah0[kc] = *(const bf16x8*)&xh[(size_t)ra0 * DD + kc * 32 + kb];
        Av0[kc] = *(const bf16x8*)&xl[(size_t)ra0 * DD + kc * 32 + kb];
        Ah1[kc] = *(const bf16x8*)&xh[(size_t)ra1 * DD + kc * 32 + kb];
        Av1[kc] = *(const bf16x8*)&xl[(size_t)ra1 * DD + kc * 32 + kb];
    }

    {   // prologue: stage chunk 0 into lds[0]
        const bf16x8* g = (const bf16x8*)wt;
        bf16x8* L = (bf16x8*)lds[0];
        #pragma unroll
        for (int i = 0; i < 4; ++i) L[t + i * 256] = g[t + i * 256];
    }

    for (int m = 0; m < 3; ++m) {
        f32x4 acc0[8], acc1[8];
        #pragma unroll
        for (int nt = 0; nt < 8; ++nt) {
            acc0[nt] = (f32x4){0.f, 0.f, 0.f, 0.f};
            acc1[nt] = (f32x4){0.f, 0.f, 0.f, 0.f};
        }

        #pragma unroll
        for (int kc = 0; kc < 4; ++kc) {
            const int q = m * 4 + kc;
            __syncthreads();
            // issue next chunk's global loads early (write-late below)
            bf16x8 st0, st1, st2, st3;
            const bool hasNext = (q < 11);
            if (hasNext) {
                const bf16x8* g = (const bf16x8*)(wt + (size_t)(q + 1) * 8192);
                st0 = g[t]; st1 = g[t + 256]; st2 = g[t + 512]; st3 = g[t + 768];
            }
            const ushort* __restrict__ L = lds[kc & 1];
            #pragma unroll
            for (int nt = 0; nt < 8; ++nt) {
                const int n = nt * 16 + l15;
                const int sw = n & 7;
                bf16x8 bh = *(const bf16x8*)&L[n * 64 + (((0 | lg) ^ sw) << 3)];
                bf16x8 bv = *(const bf16x8*)&L[n * 64 + (((4 | lg) ^ sw) << 3)];
                acc0[nt] = __builtin_amdgcn_mfma_f32_16x16x32_bf16(Ah0[kc], bh, acc0[nt], 0, 0, 0);
                acc0[nt] = __builtin_amdgcn_mfma_f32_16x16x32_bf16(Ah0[kc], bv, acc0[nt], 0, 0, 0);
                acc0[nt] = __builtin_amdgcn_mfma_f32_16x16x32_bf16(Av0[kc], bh, acc0[nt], 0, 0, 0);
                acc1[nt] = __builtin_amdgcn_mfma_f32_16x16x32_bf16(Ah1[kc], bh, acc1[nt], 0, 0, 0);
                acc1[nt] = __builtin_amdgcn_mfma_f32_16x16x32_bf16(Ah1[kc], bv, acc1[nt], 0, 0, 0);
                acc1[nt] = __builtin_amdgcn_mfma_f32_16x16x32_bf16(Av1[kc], bh, acc1[nt], 0, 0, 0);
            }
            if (hasNext) {
                bf16x8* Lw = (bf16x8*)lds[(kc & 1) ^ 1];
                Lw[t] = st0; Lw[t + 256] = st1; Lw[t + 512] = st2; Lw[t + 768] = st3;
            }
        }

        // epilogue (registers only; overlaps next chunk's global-load latency)
        if (m < 2) {
            ushort* __restrict__ fb = m ? fb1 : fb0;
            const float* __restrict__ alm = m ? al1 : al0;
            const float* __restrict__ arm = m ? ar1 : ar0;
            float* __restrict__ elm = m ? el1 : el0;
            float* __restrict__ erm = m ? er1 : er0;
            #pragma unroll
            for (int tt = 0; tt < 2; ++tt) {
                float pl[4][4], pr[4][4];
                #pragma unroll
                for (int r = 0; r < 4; ++r)
                    #pragma unroll
                    for (int h = 0; h < 4; ++h) { pl[r][h] = 0.f; pr[r][h] = 0.f; }
                #pragma unroll
                for (int nt = 0; nt < 8; ++nt) {
                    const int col = nt * 16 + l15;
                    const float wlv = alm[col], wrv = arm[col];
                    #pragma unroll
                    for (int r = 0; r < 4; ++r) {
                        const float v = tt ? acc1[nt][r] : acc0[nt][r];
                        pl[r][nt >> 1] += v * wlv;
                        pr[r][nt >> 1] += v * wrv;
                        const int row = rb + tt * 16 + lg * 4 + r;
                        if (row < NN) {
                            __hip_bfloat16 hb = __float2bfloat16(v);
                            fb[(size_t)row * DD + col] = *(ushort*)&hb;
                        }
                    }
                }
                #pragma unroll
                for (int msk = 1; msk < 16; msk <<= 1)
                    #pragma unroll
                    for (int r = 0; r < 4; ++r)
                        #pragma unroll
                        for (int h = 0; h < 4; ++h) {
                            pl[r][h] += __shfl_xor(pl[r][h], msk);
                            pr[r][h] += __shfl_xor(pr[r][h], msk);
                        }
                if (l15 < 4) {
                    #pragma unroll
                    for (int r = 0; r < 4; ++r) {
                        const int row = rb + tt * 16 + lg * 4 + r;
                        if (row < NN) {
                            const float plv = l15 == 0 ? pl[r][0] : l15 == 1 ? pl[r][1]
                                            : l15 == 2 ? pl[r][2] : pl[r][3];
                            const float prv = l15 == 0 ? pr[r][0] : l15 == 1 ? pr[r][1]
                                            : l15 == 2 ? pr[r][2] : pr[r][3];
                            elm[(size_t)row * 4 + l15] = plv;
                            erm[(size_t)row * 4 + l15] = prv;
                        }
                    }
                }
            }
        } else {
            #pragma unroll
            for (int tt = 0; tt < 2; ++tt)
                #pragma unroll
                for (int nt = 0; nt < 8; ++nt) {
                    const int col = nt * 16 + l15;
                    const float bv = bias[col];
                    #pragma unroll
                    for (int r = 0; r < 4; ++r) {
                        const int row = rb + tt * 16 + lg * 4 + r;
                        const float v = tt ? acc1[nt][r] : acc0[nt][r];
                        if (row < NN) out[(size_t)row * DD + col] = v + bv;
                    }
                }
        }
    }
}

// ---------------- aggregate: wave per dst, 4 edges in flight ------------------
__global__ __launch_bounds__(256) void agg_kernel(
    const int* __restrict__ row0, const int* __restrict__ list0,
    const float* __restrict__ el0, const float* __restrict__ er0,
    const int* __restrict__ row1, const int* __restrict__ list1,
    const float* __restrict__ el1, const float* __restrict__ er1,
    const ushort* __restrict__ fb0, const ushort* __restrict__ fb1,
    float* __restrict__ out)
{
    const int d = blockIdx.x * 4 + (threadIdx.x >> 6);
    const int lane = threadIdx.x & 63;
    if (d >= NN) return;
    const int g = lane >> 4;             // which of 4 in-flight edges
    const int l16 = lane & 15;
    const int c = l16 * 8;               // 8 output cols per lane
    const int h = l16 >> 2;              // head = col>>5

    float tot[8] = {0.f, 0.f, 0.f, 0.f, 0.f, 0.f, 0.f, 0.f};

    #pragma unroll
    for (int rel = 0; rel < 2; ++rel) {
        const int* __restrict__ rowA = rel ? row1 : row0;
        const int* __restrict__ lst  = rel ? list1 : list0;
        const float* __restrict__ elA = rel ? el1 : el0;
        const float* __restrict__ erA = rel ? er1 : er0;
        const ushort* __restrict__ fbA = rel ? fb1 : fb0;

        const int s0 = d ? rowA[d - 1] : 0, e0 = rowA[d];
        const float erh = erA[(size_t)d * 4 + h];
        float acc[8] = {0.f, 0.f, 0.f, 0.f, 0.f, 0.f, 0.f, 0.f};
        float den = 0.f;
        for (int i = s0 + g; i < e0; i += 4) {
            int s = lst[i];
            float ev = elA[(size_t)s * 4 + h] + erh;
            ev = ev > 0.f ? ev : NEG_SLOPE * ev;
            float w = __expf(ev);
            den += w;
            ushrt8 f = *(const ushrt8*)&fbA[(size_t)s * DD + c];
            #pragma unroll
            for (int q = 0; q < 8; ++q) acc[q] += w * bf2f(f[q]);
        }
        den += __shfl_xor(den, 16); den += __shfl_xor(den, 32);
        #pragma unroll
        for (int q = 0; q < 8; ++q) {
            acc[q] += __shfl_xor(acc[q], 16);
            acc[q] += __shfl_xor(acc[q], 32);
        }
        if (e0 > s0) {
            float inv = 1.f / den;
            #pragma unroll
            for (int q = 0; q < 8; ++q) tot[q] += acc[q] * inv;
        }
    }

    if (g == 0) {
        float4 o1 = *(float4*)&out[(size_t)d * DD + c];
        float4 o2 = *(float4*)&out[(size_t)d * DD + c + 4];
        o1.x = fmaxf(o1.x + tot[0], 0.f); o1.y = fmaxf(o1.y + tot[1], 0.f);
        o1.z = fmaxf(o1.z + tot[2], 0.f); o1.w = fmaxf(o1.w + tot[3], 0.f);
        o2.x = fmaxf(o2.x + tot[4], 0.f); o2.y = fmaxf(o2.y + tot[5], 0.f);
        o2.z = fmaxf(o2.z + tot[6], 0.f); o2.w = fmaxf(o2.w + tot[7], 0.f);
        *(float4*)&out[(size_t)d * DD + c] = o1;
        *(float4*)&out[(size_t)d * DD + c + 4] = o2;
    }
}

extern "C" void kernel_launch(void* const* d_in, const int* in_sizes, int n_in,
                              void* d_out, int out_size, void* d_ws, size_t ws_size,
                              hipStream_t stream)
{
    const float* x    = (const float*)d_in[0];
    const float* W0   = (const float*)d_in[1];
    const float* al0  = (const float*)d_in[2];
    const float* ar0  = (const float*)d_in[3];
    const float* W1   = (const float*)d_in[4];
    const float* al1  = (const float*)d_in[5];
    const float* ar1  = (const float*)d_in[6];
    const float* Wl   = (const float*)d_in[7];
    const float* bias = (const float*)d_in[8];
    const int* src0   = (const int*)d_in[9];
    const int* dst0   = (const int*)d_in[10];
    const int* src1   = (const int*)d_in[11];
    const int* dst1   = (const int*)d_in[12];
    float* out = (float*)d_out;

    // workspace layout
    ushort* wsu = (ushort*)d_ws;
    ushort* xh  = wsu;                          // N*128
    ushort* xl  = xh + (size_t)NN * DD;
    ushort* fb0 = xl + (size_t)NN * DD;
    ushort* fb1 = fb0 + (size_t)NN * DD;
    ushort* wt  = fb1 + (size_t)NN * DD;        // 12 chunks * 8192
    float* fbase = (float*)(wt + 12 * 8192);
    float* el0  = fbase;
    float* er0  = el0 + (size_t)NN * HH;
    float* el1  = er0 + (size_t)NN * HH;
    float* er1  = el1 + (size_t)NN * HH;
    int* hist   = (int*)(er1 + (size_t)NN * HH);
    int* base   = hist + NSEG;
    int* row0   = base + NSEG;
    int* row1   = row0 + NN;
    unsigned int* pk = (unsigned int*)(row1 + NN);   // 2*E
    int* list   = (int*)(pk + (size_t)2 * EE);       // 2*E
    int* list0  = list;
    int* list1  = list + EE;

    prep_kernel<<<dim3(XB + WB + 2 * NBLK), dim3(256), 0, stream>>>(
        x, W0, W1, Wl, dst0, dst1, xh, xl, wt, hist);

    scan_kernel<<<dim3(1), dim3(256), 0, stream>>>(hist, base);

    bucket_kernel<<<dim3(2 * NBLK), dim3(256), 0, stream>>>(
        src0, dst0, src1, dst1, base, pk);

    sort_kernel<<<dim3(2 * NBUCK), dim3(256), 0, stream>>>(
        pk, base, row0, row1, list);

    proj_kernel<<<dim3((NN + 127) / 128), dim3(256), 0, stream>>>(
        xh, xl, wt, al0, ar0, al1, ar1, bias,
        fb0, fb1, el0, er0, el1, er1, out);

    agg_kernel<<<dim3((NN + 3) / 4), dim3(256), 0, stream>>>(
        row0, list0, el0, er0, row1, list1, el1, er1, fb0, fb1, out);
}

// Round 7
// 217.175 us; speedup vs baseline: 8.5147x; 1.0304x over previous
//
#include <hip/hip_runtime.h>
#include <hip/hip_bf16.h>

#define NN 50000
#define EE 800000
#define DD 128
#define HH 4
#define NEG_SLOPE 0.2f

#define BSH 9                 // bucket = dst >> 9 (512 dsts)
#define NBUCK 98              // ceil(50000/512)
#define CH 8192               // edges per chunk
#define NBLK 98               // ceil(800000/8192)
#define NSEG (2 * NBUCK * NBLK)   // 19208 flat scan cells
#define BKB (2 * NBLK)        // 196 bucket blocks in fused kernel
#define PJB ((NN + 127) / 128)    // 391 proj blocks

typedef __attribute__((ext_vector_type(8))) short bf16x8;
typedef __attribute__((ext_vector_type(4))) float f32x4;
typedef __attribute__((ext_vector_type(8))) unsigned short ushrt8;

static __device__ __forceinline__ float bf2f(ushort u) {
    union { unsigned int ui; float f; } v; v.ui = ((unsigned int)u) << 16; return v.f;
}
static __device__ __forceinline__ void split1(float v, ushort& h, ushort& l) {
    __hip_bfloat16 hb = __float2bfloat16(v);
    float hf = __bfloat162float(hb);
    __hip_bfloat16 lb = __float2bfloat16(v - hf);
    h = *(ushort*)&hb; l = *(ushort*)&lb;
}

// ---------------- prep: xcvt (6250) + wcvt (192) + bucket-hist (196) ----------
// wt layout: 12 chunks (m*4+kc) of 16KB: [n=128][slot'=8][8 ushorts],
// slot = hl*4 + kin8, slot' = slot ^ (n&7)  -- swizzle baked in for LDS.
#define XB 6250
#define WB 192
__global__ __launch_bounds__(256) void prep_kernel(
    const float* __restrict__ x,
    const float* __restrict__ W0, const float* __restrict__ W1,
    const float* __restrict__ Wl,
    const int* __restrict__ dst0, const int* __restrict__ dst1,
    ushort* __restrict__ xh, ushort* __restrict__ xl, ushort* __restrict__ wt,
    int* __restrict__ hist)
{
    const int b = blockIdx.x;
    const int t = threadIdx.x;
    if (b < XB) {                                  // x -> (hi, lo) bf16 split
        int i = b * 256 + t;                       // float4 idx, exact 1.6M
        float4 v = ((const float4*)x)[i];
        ushort4 h, l;
        split1(v.x, h.x, l.x); split1(v.y, h.y, l.y);
        split1(v.z, h.z, l.z); split1(v.w, h.w, l.w);
        *(ushort4*)&xh[(size_t)i * 4] = h;
        *(ushort4*)&xl[(size_t)i * 4] = l;
    } else if (b < XB + WB) {                      // W -> pre-swizzled chunks
        int idx = (b - XB) * 256 + t;              // 0..49151
        int m = idx >> 14, e = idx & 16383;
        const float* W = (m == 0) ? W0 : (m == 1) ? W1 : Wl;
        int k = e >> 7, n = e & 127;               // W[k][n]
        ushort h, l; split1(W[e], h, l);
        int q = m * 4 + (k >> 5);
        int kin8 = (k >> 3) & 3, ke = k & 7;
        int sw = n & 7;
        size_t base = (size_t)q * 8192 + n * 64;
        wt[base + (((0 | kin8) ^ sw) << 3) + ke] = h;
        wt[base + (((4 | kin8) ^ sw) << 3) + ke] = l;
    } else {                                       // per-chunk bucket histogram
        __shared__ int cnt[NBUCK];
        int hb = b - XB - WB;                      // 0..195
        int rel = hb >= NBLK;
        int ci = hb - rel * NBLK;
        const int* __restrict__ dstA = rel ? dst1 : dst0;
        if (t < NBUCK) cnt[t] = 0;
        __syncthreads();
        int lo = ci * CH, hi = min(lo + CH, EE);
        for (int i = lo + t; i < hi; i += 256)
            atomicAdd(&cnt[dstA[i] >> BSH], 1);
        __syncthreads();
        if (t < NBUCK)
            hist[((rel * NBUCK) + t) * NBLK + ci] = cnt[t];
    }
}

// ---------------- flat exclusive scan of hist -> base -------------------------
__global__ __launch_bounds__(256) void scan_kernel(
    const int* __restrict__ hist, int* __restrict__ base)
{
    __shared__ int wq[4];
    const int t = threadIdx.x;
    const int lane = t & 63, wv = t >> 6;
    const int st = t * 76;
    const int en = min(st + 76, NSEG);
    int sum = 0;
    for (int i = st; i < en; ++i) sum += hist[i];
    int incl = sum;
    #pragma unroll
    for (int off = 1; off < 64; off <<= 1) {
        int u = __shfl_up(incl, off);
        if (lane >= off) incl += u;
    }
    if (lane == 63) wq[wv] = incl;
    __syncthreads();
    int woff = 0;
    #pragma unroll
    for (int w = 0; w < 4; ++w) woff += (w < wv) ? wq[w] : 0;
    int run = woff + incl - sum;                   // exclusive prefix
    for (int i = st; i < en; ++i) { base[i] = run; run += hist[i]; }
}

// ---------------- fused: bucket scatter (blocks 0..195) + proj (196..586) -----
__global__ __launch_bounds__(256) void projbucket_kernel(
    const int* __restrict__ src0, const int* __restrict__ dst0,
    const int* __restrict__ src1, const int* __restrict__ dst1,
    const int* __restrict__ base, unsigned int* __restrict__ pk,
    const ushort* __restrict__ xh, const ushort* __restrict__ xl,
    const ushort* __restrict__ wt,
    const float* __restrict__ al0, const float* __restrict__ ar0,
    const float* __restrict__ al1, const float* __restrict__ ar1,
    const float* __restrict__ bias,
    ushort* __restrict__ fb0, ushort* __restrict__ fb1,
    float* __restrict__ el0, float* __restrict__ er0,
    float* __restrict__ el1, float* __restrict__ er1,
    float* __restrict__ out)
{
    __shared__ ushort lds[2][8192];               // proj: 2 x 16KB W chunks
    const int t = threadIdx.x;

    if (blockIdx.x < BKB) {
        // ------------- bucket scatter -------------
        int* cnt = (int*)&lds[0][0];              // alias LDS
        int* bs  = cnt + 128;
        const int hb = blockIdx.x;
        const int rel = hb >= NBLK;
        const int ci = hb - rel * NBLK;
        const int* __restrict__ srcA = rel ? src1 : src0;
        const int* __restrict__ dstA = rel ? dst1 : dst0;
        if (t < NBUCK) {
            cnt[t] = 0;
            bs[t] = base[((rel * NBUCK) + t) * NBLK + ci];
        }
        __syncthreads();
        int lo = ci * CH, hi = min(lo + CH, EE);
        for (int i = lo + t; i < hi; i += 256) {
            int dd = dstA[i], ss = srcA[i];
            int bk = dd >> BSH;
            int rk = atomicAdd(&cnt[bk], 1);
            pk[bs[bk] + rk] = (unsigned int)ss | ((unsigned int)(dd & 511) << 17);
        }
        return;
    }

    // ------------- proj -------------
    const int pb = blockIdx.x - BKB;
    const int lane = t & 63, wave = t >> 6;
    const int l15 = lane & 15, lg = lane >> 4;
    const int rb = pb * 128 + wave * 32;

    int ra0 = rb + l15;      if (ra0 > NN - 1) ra0 = NN - 1;
    int ra1 = rb + 16 + l15; if (ra1 > NN - 1) ra1 = NN - 1;
    const int kb = lg * 8;

    bf16x8 Ah0[4], Av0[4], Ah1[4], Av1[4];
    #pragma unroll
    for (int kc = 0; kc < 4; ++kc) {
        Ah0[kc] = *(const bf16x8*)&xh[(size_t)ra0 * DD + kc * 32 + kb];
        Av0[kc] = *(const bf16x8*)&xl[(size_t)ra0 * DD + kc * 32 + kb];
        Ah1[kc] = *(const bf16x8*)&xh[(size_t)ra1 * DD + kc * 32 + kb];
        Av1[kc] = *(const bf16x8*)&xl[(size_t)ra1 * DD + kc * 32 + kb];
    }

    {   // prologue: stage chunk 0 into lds[0]
        const bf16x8* g = (const bf16x8*)wt;
        bf16x8* L = (bf16x8*)lds[0];
        #pragma unroll
        for (int i = 0; i < 4; ++i) L[t + i * 256] = g[t + i * 256];
    }

    for (int m = 0; m < 3; ++m) {
        f32x4 acc0[8], acc1[8];
        #pragma unroll
        for (int nt = 0; nt < 8; ++nt) {
            acc0[nt] = (f32x4){0.f, 0.f, 0.f, 0.f};
            acc1[nt] = (f32x4){0.f, 0.f, 0.f, 0.f};
        }

        #pragma unroll
        for (int kc = 0; kc < 4; ++kc) {
            const int q = m * 4 + kc;
            __syncthreads();
            bf16x8 st0, st1, st2, st3;
            const bool hasNext = (q < 11);
            if (hasNext) {
                const bf16x8* g = (const bf16x8*)(wt + (size_t)(q + 1) * 8192);
                st0 = g[t]; st1 = g[t + 256]; st2 = g[t + 512]; st3 = g[t + 768];
            }
            const ushort* __restrict__ L = lds[kc & 1];
            #pragma unroll
            for (int nt = 0; nt < 8; ++nt) {
                const int n = nt * 16 + l15;
                const int sw = n & 7;
                bf16x8 bh = *(const bf16x8*)&L[n * 64 + (((0 | lg) ^ sw) << 3)];
                bf16x8 bv = *(const bf16x8*)&L[n * 64 + (((4 | lg) ^ sw) << 3)];
                acc0[nt] = __builtin_amdgcn_mfma_f32_16x16x32_bf16(Ah0[kc], bh, acc0[nt], 0, 0, 0);
                acc0[nt] = __builtin_amdgcn_mfma_f32_16x16x32_bf16(Ah0[kc], bv, acc0[nt], 0, 0, 0);
                acc0[nt] = __builtin_amdgcn_mfma_f32_16x16x32_bf16(Av0[kc], bh, acc0[nt], 0, 0, 0);
                acc1[nt] = __builtin_amdgcn_mfma_f32_16x16x32_bf16(Ah1[kc], bh, acc1[nt], 0, 0, 0);
                acc1[nt] = __builtin_amdgcn_mfma_f32_16x16x32_bf16(Ah1[kc], bv, acc1[nt], 0, 0, 0);
                acc1[nt] = __builtin_amdgcn_mfma_f32_16x16x32_bf16(Av1[kc], bh, acc1[nt], 0, 0, 0);
            }
            if (hasNext) {
                bf16x8* Lw = (bf16x8*)lds[(kc & 1) ^ 1];
                Lw[t] = st0; Lw[t + 256] = st1; Lw[t + 512] = st2; Lw[t + 768] = st3;
            }
        }

        if (m < 2) {
            ushort* __restrict__ fb = m ? fb1 : fb0;
            const float* __restrict__ alm = m ? al1 : al0;
            const float* __restrict__ arm = m ? ar1 : ar0;
            float* __restrict__ elm = m ? el1 : el0;
            float* __restrict__ erm = m ? er1 : er0;
            #pragma unroll
            for (int tt = 0; tt < 2; ++tt) {
                float pl[4][4], pr[4][4];
                #pragma unroll
                for (int r = 0; r < 4; ++r)
                    #pragma unroll
                    for (int h = 0; h < 4; ++h) { pl[r][h] = 0.f; pr[r][h] = 0.f; }
                #pragma unroll
                for (int nt = 0; nt < 8; ++nt) {
                    const int col = nt * 16 + l15;
                    const float wlv = alm[col], wrv = arm[col];
                    #pragma unroll
                    for (int r = 0; r < 4; ++r) {
                        const float v = tt ? acc1[nt][r] : acc0[nt][r];
                        pl[r][nt >> 1] += v * wlv;
                        pr[r][nt >> 1] += v * wrv;
                        const int row = rb + tt * 16 + lg * 4 + r;
                        if (row < NN) {
                            __hip_bfloat16 hb = __float2bfloat16(v);
                            fb[(size_t)row * DD + col] = *(ushort*)&hb;
                        }
                    }
                }
                #pragma unroll
                for (int msk = 1; msk < 16; msk <<= 1)
                    #pragma unroll
                    for (int r = 0; r < 4; ++r)
                        #pragma unroll
                        for (int h = 0; h < 4; ++h) {
                            pl[r][h] += __shfl_xor(pl[r][h], msk);
                            pr[r][h] += __shfl_xor(pr[r][h], msk);
                        }
                if (l15 < 4) {
                    #pragma unroll
                    for (int r = 0; r < 4; ++r) {
                        const int row = rb + tt * 16 + lg * 4 + r;
                        if (row < NN) {
                            const float plv = l15 == 0 ? pl[r][0] : l15 == 1 ? pl[r][1]
                                            : l15 == 2 ? pl[r][2] : pl[r][3];
                            const float prv = l15 == 0 ? pr[r][0] : l15 == 1 ? pr[r][1]
                                            : l15 == 2 ? pr[r][2] : pr[r][3];
                            elm[(size_t)row * 4 + l15] = plv;
                            erm[(size_t)row * 4 + l15] = prv;
                        }
                    }
                }
            }
        } else {
            #pragma unroll
            for (int tt = 0; tt < 2; ++tt)
                #pragma unroll
                for (int nt = 0; nt < 8; ++nt) {
                    const int col = nt * 16 + l15;
                    const float bv = bias[col];
                    #pragma unroll
                    for (int r = 0; r < 4; ++r) {
                        const int row = rb + tt * 16 + lg * 4 + r;
                        const float v = tt ? acc1[nt][r] : acc0[nt][r];
                        if (row < NN) out[(size_t)row * DD + col] = v + bv;
                    }
                }
        }
    }
}

// ---------------- per-bucket counting sort -> CSR row + list ------------------
__global__ __launch_bounds__(256) void sort_kernel(
    const unsigned int* __restrict__ pk, const int* __restrict__ base,
    int* __restrict__ row0, int* __restrict__ row1, int* __restrict__ list)
{
    __shared__ int cnt[512];
    __shared__ int offs[512];
    __shared__ int wq[4];
    const int hb = blockIdx.x;
    const int t = threadIdx.x;
    const int lane = t & 63, wv = t >> 6;
    const int rel = hb >= NBUCK;
    const int bk = hb - rel * NBUCK;

    const int fs = base[((rel * NBUCK) + bk) * NBLK];
    const int fe = (rel == 1 && bk == NBUCK - 1) ? 2 * EE
                 : base[((rel * NBUCK) + bk + 1) * NBLK];

    cnt[t] = 0; cnt[t + 256] = 0;
    __syncthreads();
    for (int i = fs + t; i < fe; i += 256)
        atomicAdd(&cnt[pk[i] >> 17], 1);
    __syncthreads();

    int a = cnt[2 * t], bvl = cnt[2 * t + 1];
    int ps = a + bvl;
    int incl = ps;
    #pragma unroll
    for (int off = 1; off < 64; off <<= 1) {
        int u = __shfl_up(incl, off);
        if (lane >= off) incl += u;
    }
    if (lane == 63) wq[wv] = incl;
    __syncthreads();
    int woff = 0;
    #pragma unroll
    for (int w = 0; w < 4; ++w) woff += (w < wv) ? wq[w] : 0;
    int excl = woff + incl - ps;
    offs[2 * t] = excl;
    offs[2 * t + 1] = excl + a;
    __syncthreads();

    int* __restrict__ row = rel ? row1 : row0;
    const int fsLocal = fs - (rel ? EE : 0);
    const int d0 = bk << BSH;
    for (int j = t; j < 512; j += 256) {
        int d = d0 + j;
        if (d < NN) row[d] = fsLocal + offs[j] + cnt[j];
    }
    __syncthreads();

    for (int i = fs + t; i < fe; i += 256) {
        unsigned int u = pk[i];
        int ld = u >> 17;
        int p = atomicAdd(&offs[ld], 1);
        list[fs + p] = (int)(u & 0x1FFFF);
    }
}

// ---------------- aggregate: wave per dst, software-pipelined gather ----------
__global__ __launch_bounds__(256) void agg_kernel(
    const int* __restrict__ row0, const int* __restrict__ list0,
    const float* __restrict__ el0, const float* __restrict__ er0,
    const int* __restrict__ row1, const int* __restrict__ list1,
    const float* __restrict__ el1, const float* __restrict__ er1,
    const ushort* __restrict__ fb0, const ushort* __restrict__ fb1,
    float* __restrict__ out)
{
    const int d = blockIdx.x * 4 + (threadIdx.x >> 6);
    const int lane = threadIdx.x & 63;
    if (d >= NN) return;
    const int g = lane >> 4;             // 4 edge slots, pipelined 2-deep
    const int l16 = lane & 15;
    const int c = l16 * 8;               // 8 output cols per lane
    const int h = l16 >> 2;              // head = col>>5

    float tot[8] = {0.f, 0.f, 0.f, 0.f, 0.f, 0.f, 0.f, 0.f};

    #pragma unroll
    for (int rel = 0; rel < 2; ++rel) {
        const int* __restrict__ rowA = rel ? row1 : row0;
        const int* __restrict__ lst  = rel ? list1 : list0;
        const float* __restrict__ elA = rel ? el1 : el0;
        const float* __restrict__ erA = rel ? er1 : er0;
        const ushort* __restrict__ fbA = rel ? fb1 : fb0;

        const int s0 = d ? rowA[d - 1] : 0, e0 = rowA[d];
        const float erh = erA[(size_t)d * 4 + h];
        float acc[8] = {0.f, 0.f, 0.f, 0.f, 0.f, 0.f, 0.f, 0.f};
        float den = 0.f;

        int i = s0 + g;
        float elvA = 0.f;
        ushrt8 fA = (ushrt8){0, 0, 0, 0, 0, 0, 0, 0};
        if (i < e0) {
            int s = lst[i];
            elvA = elA[(size_t)s * 4 + h];
            fA = *(const ushrt8*)&fbA[(size_t)s * DD + c];
        }
        while (i < e0) {
            const int inext = i + 4;
            float elvB = 0.f;
            ushrt8 fB = (ushrt8){0, 0, 0, 0, 0, 0, 0, 0};
            if (inext < e0) {                      // issue next edge's loads early
                int s = lst[inext];
                elvB = elA[(size_t)s * 4 + h];
                fB = *(const ushrt8*)&fbA[(size_t)s * DD + c];
            }
            float ev = elvA + erh;
            ev = ev > 0.f ? ev : NEG_SLOPE * ev;
            float w = __expf(ev);
            den += w;
            #pragma unroll
            for (int q = 0; q < 8; ++q) acc[q] += w * bf2f(fA[q]);
            i = inext; elvA = elvB; fA = fB;
        }

        den += __shfl_xor(den, 16); den += __shfl_xor(den, 32);
        #pragma unroll
        for (int q = 0; q < 8; ++q) {
            acc[q] += __shfl_xor(acc[q], 16);
            acc[q] += __shfl_xor(acc[q], 32);
        }
        if (e0 > s0) {
            float inv = 1.f / den;
            #pragma unroll
            for (int q = 0; q < 8; ++q) tot[q] += acc[q] * inv;
        }
    }

    if (g == 0) {
        float4 o1 = *(float4*)&out[(size_t)d * DD + c];
        float4 o2 = *(float4*)&out[(size_t)d * DD + c + 4];
        o1.x = fmaxf(o1.x + tot[0], 0.f); o1.y = fmaxf(o1.y + tot[1], 0.f);
        o1.z = fmaxf(o1.z + tot[2], 0.f); o1.w = fmaxf(o1.w + tot[3], 0.f);
        o2.x = fmaxf(o2.x + tot[4], 0.f); o2.y = fmaxf(o2.y + tot[5], 0.f);
        o2.z = fmaxf(o2.z + tot[6], 0.f); o2.w = fmaxf(o2.w + tot[7], 0.f);
        *(float4*)&out[(size_t)d * DD + c] = o1;
        *(float4*)&out[(size_t)d * DD + c + 4] = o2;
    }
}

extern "C" void kernel_launch(void* const* d_in, const int* in_sizes, int n_in,
                              void* d_out, int out_size, void* d_ws, size_t ws_size,
                              hipStream_t stream)
{
    const float* x    = (const float*)d_in[0];
    const float* W0   = (const float*)d_in[1];
    const float* al0  = (const float*)d_in[2];
    const float* ar0  = (const float*)d_in[3];
    const float* W1   = (const float*)d_in[4];
    const float* al1  = (const float*)d_in[5];
    const float* ar1  = (const float*)d_in[6];
    const float* Wl   = (const float*)d_in[7];
    const float* bias = (const float*)d_in[8];
    const int* src0   = (const int*)d_in[9];
    const int* dst0   = (const int*)d_in[10];
    const int* src1   = (const int*)d_in[11];
    const int* dst1   = (const int*)d_in[12];
    float* out = (float*)d_out;

    // workspace layout
    ushort* wsu = (ushort*)d_ws;
    ushort* xh  = wsu;                          // N*128
    ushort* xl  = xh + (size_t)NN * DD;
    ushort* fb0 = xl + (size_t)NN * DD;
    ushort* fb1 = fb0 + (size_t)NN * DD;
    ushort* wt  = fb1 + (size_t)NN * DD;        // 12 chunks * 8192
    float* fbase = (float*)(wt + 12 * 8192);
    float* el0  = fbase;
    float* er0  = el0 + (size_t)NN * HH;
    float* el1  = er0 + (size_t)NN * HH;
    float* er1  = el1 + (size_t)NN * HH;
    int* hist   = (int*)(er1 + (size_t)NN * HH);
    int* base   = hist + NSEG;
    int* row0   = base + NSEG;
    int* row1   = row0 + NN;
    unsigned int* pk = (unsigned int*)(row1 + NN);   // 2*E
    int* list   = (int*)(pk + (size_t)2 * EE);       // 2*E
    int* list0  = list;
    int* list1  = list + EE;

    prep_kernel<<<dim3(XB + WB + 2 * NBLK), dim3(256), 0, stream>>>(
        x, W0, W1, Wl, dst0, dst1, xh, xl, wt, hist);

    scan_kernel<<<dim3(1), dim3(256), 0, stream>>>(hist, base);

    projbucket_kernel<<<dim3(BKB + PJB), dim3(256), 0, stream>>>(
        src0, dst0, src1, dst1, base, pk,
        xh, xl, wt, al0, ar0, al1, ar1, bias,
        fb0, fb1, el0, er0, el1, er1, out);

    sort_kernel<<<dim3(2 * NBUCK), dim3(256), 0, stream>>>(
        pk, base, row0, row1, list);

    agg_kernel<<<dim3((NN + 3) / 4), dim3(256), 0, stream>>>(
        row0, list0, el0, er0, row1, list1, el1, er1, fb0, fb1, out);
}